// Round 1
// baseline (1125.198 us; speedup 1.0000x reference)
//
#include <hip/hip_runtime.h>
#include <stdint.h>

// GNNAutoEncoder: 2x SAGEConv(mean) + edge MLP decoder.
// N=100000 nodes, E=1600000 edges, D=256, HIDDEN=256, OUT=128.
static constexpr int NN = 100000;
static constexpr int NE = 1600000;

typedef __bf16 bf16;
typedef __bf16 bf16x4 __attribute__((ext_vector_type(4)));
typedef __bf16 bf16x8 __attribute__((ext_vector_type(8)));
typedef float floatx4 __attribute__((ext_vector_type(4)));

// async global->LDS, 16B per lane. LDS dest must be wave-uniform base; HW
// writes lane i at base + i*16.
__device__ __forceinline__ void async16(const void* g, void* l) {
  __builtin_amdgcn_global_load_lds(
      (const __attribute__((address_space(1))) void*)g,
      (__attribute__((address_space(3))) void*)l, 16, 0, 0);
}

// ---------------- CSR build ----------------
__global__ void k_hist(const int* __restrict__ dst, int* __restrict__ cnt, int E) {
  int e = blockIdx.x * 256 + threadIdx.x;
  if (e < E) atomicAdd(&cnt[dst[e]], 1);
}

__global__ __launch_bounds__(1024) void k_scan(const int* __restrict__ cnt,
                                               int* __restrict__ rowptr, int N) {
  __shared__ int sh[1024];
  int t = threadIdx.x;
  int chunk = (N + 1023) >> 10;
  int b = t * chunk;
  int e = b + chunk; if (e > N) e = N;
  int s = 0;
  for (int i = b; i < e; ++i) s += cnt[i];
  sh[t] = s;
  __syncthreads();
  for (int off = 1; off < 1024; off <<= 1) {
    int v = (t >= off) ? sh[t - off] : 0;
    __syncthreads();
    sh[t] += v;
    __syncthreads();
  }
  int run = sh[t] - s;  // exclusive prefix
  for (int i = b; i < e; ++i) { rowptr[i] = run; run += cnt[i]; }
  if (b < N && e == N) rowptr[N] = run;  // exactly one thread
}

__global__ void k_fill(const int* __restrict__ src, const int* __restrict__ dst,
                       const int* __restrict__ rowptr, int* __restrict__ cursor,
                       int* __restrict__ csr, int E) {
  int e = blockIdx.x * 256 + threadIdx.x;
  if (e < E) {
    int d = dst[e];
    int pos = rowptr[d] + atomicAdd(&cursor[d], 1);
    csr[pos] = src[e];
  }
}

// ---------------- dtype converts ----------------
__global__ void k_cvt_x(const float* __restrict__ x, bf16* __restrict__ xb) {
  int t = blockIdx.x * 256 + threadIdx.x;  // 4 elems / thread
  const float4 v = ((const float4*)x)[t];
  bf16x4 o;
  o.x = (bf16)v.x; o.y = (bf16)v.y; o.z = (bf16)v.z; o.w = (bf16)v.w;
  ((bf16x4*)xb)[t] = o;
}

// B1 = [W1l | W1r] as [256][512]; B2 = [W2l | W2r] as [128][512]; Bd = Wd1 [128][256]
__global__ void k_cvt_w(const float* __restrict__ W1l, const float* __restrict__ W1r,
                        const float* __restrict__ W2l, const float* __restrict__ W2r,
                        const float* __restrict__ Wd1,
                        bf16* __restrict__ B1, bf16* __restrict__ B2, bf16* __restrict__ Bd) {
  int g = blockIdx.x * 256 + threadIdx.x;  // 229376 total
  if (g < 131072) {
    int o = g >> 9, k = g & 511;
    float v = (k < 256) ? W1l[o * 256 + k] : W1r[o * 256 + k - 256];
    B1[g] = (bf16)v;
  } else if (g < 131072 + 65536) {
    int t = g - 131072;
    int o = t >> 9, k = t & 511;
    float v = (k < 256) ? W2l[o * 256 + k] : W2r[o * 256 + k - 256];
    B2[t] = (bf16)v;
  } else {
    int t = g - 131072 - 65536;
    Bd[t] = (bf16)Wd1[t];
  }
}

// ---------------- mean aggregation (CSR gather) ----------------
// one wave per node; lane covers 4 of 256 cols. feat is bf16 [N][256].
__global__ void k_agg(const bf16* __restrict__ feat, const int* __restrict__ rowptr,
                      const int* __restrict__ csr, bf16* __restrict__ mean) {
  int wave = threadIdx.x >> 6, lane = threadIdx.x & 63;
  int n = blockIdx.x * 4 + wave;
  int s = rowptr[n], e = rowptr[n + 1];
  float ax = 0.f, ay = 0.f, az = 0.f, aw = 0.f;
  const bf16* base = feat + (size_t)lane * 4;
  for (int i = s; i < e; ++i) {
    int sn = csr[i];
    bf16x4 v = *(const bf16x4*)(base + (size_t)sn * 256);
    ax += (float)v.x; ay += (float)v.y; az += (float)v.z; aw += (float)v.w;
  }
  int deg = e - s;
  float sc = 1.0f / (float)(deg > 0 ? deg : 1);
  bf16x4 o;
  o.x = (bf16)(ax * sc); o.y = (bf16)(ay * sc);
  o.z = (bf16)(az * sc); o.w = (bf16)(aw * sc);
  *(bf16x4*)(mean + (size_t)n * 256 + lane * 4) = o;
}

// ---------------- SAGEConv GEMM: out = act([A1|A2] @ B^T + bias) ----------------
// A1,A2: bf16 [Nrows][256] each (K=512 concat). B: bf16 [NOUT_TOT][512].
// Tile: BM=128 rows x BN=128 cols (blockIdx.y selects col tile), BK=64, 4 waves 2x2.
template <int NOUT_TOT, bool RELU>
__global__ __launch_bounds__(256) void k_conv_gemm(
    const bf16* __restrict__ A1, const bf16* __restrict__ A2,
    const bf16* __restrict__ B, const float* __restrict__ bias,
    bf16* __restrict__ out, int Nrows) {
  __shared__ bf16 As[128 * 64];
  __shared__ bf16 Bs[128 * 64];
  const int tid = threadIdx.x, wave = tid >> 6, lane = tid & 63;
  const int quad = lane >> 4, l16 = lane & 15;
  const int rowBase = blockIdx.x * 128;
  const int colBase = blockIdx.y * 128;
  const int wr = (wave >> 1) * 64;  // wave row offset within tile
  const int wc = (wave & 1) * 64;   // wave col offset
  floatx4 acc[4][4] = {};

  for (int kc = 0; kc < 8; ++kc) {
    const bf16* Asrc = (kc < 4) ? A1 : A2;
    const int kb = (kc & 3) * 64;
    // stage A tile 128x64 (16KB = 1024 x 16B units; 4 iters/wave)
    for (int i = 0; i < 4; ++i) {
      int u = wave * 256 + i * 64 + lane;
      int row = u >> 3, seg = u & 7;
      int node = rowBase + row;
      if (node >= Nrows) node = Nrows - 1;
      async16(Asrc + (size_t)node * 256 + kb + seg * 8, &As[(wave * 256 + i * 64) * 8]);
    }
    // stage B tile 128x64
    for (int i = 0; i < 4; ++i) {
      int u = wave * 256 + i * 64 + lane;
      int row = u >> 3, seg = u & 7;
      async16(B + (size_t)(colBase + row) * 512 + kc * 64 + seg * 8,
              &Bs[(wave * 256 + i * 64) * 8]);
    }
    __syncthreads();
    for (int ks = 0; ks < 2; ++ks) {
      bf16x8 af[4], bq[4];
      for (int mt = 0; mt < 4; ++mt)
        af[mt] = *(const bf16x8*)&As[(wr + mt * 16 + l16) * 64 + ks * 32 + quad * 8];
      for (int nt = 0; nt < 4; ++nt)
        bq[nt] = *(const bf16x8*)&Bs[(wc + nt * 16 + l16) * 64 + ks * 32 + quad * 8];
      for (int mt = 0; mt < 4; ++mt)
        for (int nt = 0; nt < 4; ++nt)
          acc[mt][nt] = __builtin_amdgcn_mfma_f32_16x16x32_bf16(af[mt], bq[nt], acc[mt][nt], 0, 0, 0);
    }
    __syncthreads();
  }
  // epilogue: C/D layout col=lane&15, row=quad*4+reg
  float bv[4];
  for (int nt = 0; nt < 4; ++nt) bv[nt] = bias[colBase + wc + nt * 16 + l16];
  for (int mt = 0; mt < 4; ++mt)
    for (int nt = 0; nt < 4; ++nt) {
      int gcol = colBase + wc + nt * 16 + l16;
      for (int r = 0; r < 4; ++r) {
        int grow = rowBase + wr + mt * 16 + quad * 4 + r;
        if (grow < Nrows) {
          float v = acc[mt][nt][r] + bv[nt];
          if (RELU) v = fmaxf(v, 0.0f);
          out[(size_t)grow * NOUT_TOT + gcol] = (bf16)v;
        }
      }
    }
}

// ---------------- edge decoder ----------------
// per edge: zc=[z[src]|z[dst]] (256), hd=relu(zc@Wd1^T+bd1), out=hd.wd2+bd2.
// BM=128 edges (E%128==0), BN=128 (all outputs), BK=64, K=256, fused epilogue.
__global__ __launch_bounds__(256) void k_decoder(
    const bf16* __restrict__ z, const int* __restrict__ src, const int* __restrict__ dstv,
    const bf16* __restrict__ Bd, const float* __restrict__ bd1,
    const float* __restrict__ wd2, const float* __restrict__ bd2,
    float* __restrict__ out) {
  __shared__ bf16 As[128 * 64];
  __shared__ bf16 Bs[128 * 64];
  __shared__ int ids[2][128];
  __shared__ float osum[128];
  const int tid = threadIdx.x, wave = tid >> 6, lane = tid & 63;
  const int quad = lane >> 4, l16 = lane & 15;
  const int base = blockIdx.x * 128;
  if (tid < 128) ids[0][tid] = src[base + tid];
  else           ids[1][tid - 128] = dstv[base + tid - 128];
  __syncthreads();
  const int wr = (wave >> 1) * 64, wc = (wave & 1) * 64;
  floatx4 acc[4][4] = {};

  for (int kc = 0; kc < 4; ++kc) {
    const int side = kc >> 1;          // 0: src half, 1: dst half
    const int kb = (kc & 1) * 64;      // col offset within z row
    for (int i = 0; i < 4; ++i) {
      int u = wave * 256 + i * 64 + lane;
      int row = u >> 3, seg = u & 7;
      int node = ids[side][row];
      async16(z + (size_t)node * 128 + kb + seg * 8, &As[(wave * 256 + i * 64) * 8]);
    }
    for (int i = 0; i < 4; ++i) {
      int u = wave * 256 + i * 64 + lane;
      int row = u >> 3, seg = u & 7;
      async16(Bd + (size_t)row * 256 + kc * 64 + seg * 8, &Bs[(wave * 256 + i * 64) * 8]);
    }
    __syncthreads();
    for (int ks = 0; ks < 2; ++ks) {
      bf16x8 af[4], bq[4];
      for (int mt = 0; mt < 4; ++mt)
        af[mt] = *(const bf16x8*)&As[(wr + mt * 16 + l16) * 64 + ks * 32 + quad * 8];
      for (int nt = 0; nt < 4; ++nt)
        bq[nt] = *(const bf16x8*)&Bs[(wc + nt * 16 + l16) * 64 + ks * 32 + quad * 8];
      for (int mt = 0; mt < 4; ++mt)
        for (int nt = 0; nt < 4; ++nt)
          acc[mt][nt] = __builtin_amdgcn_mfma_f32_16x16x32_bf16(af[mt], bq[nt], acc[mt][nt], 0, 0, 0);
    }
    __syncthreads();
  }
  if (tid < 128) osum[tid] = 0.0f;
  float b1v[4], w2v[4];
  for (int nt = 0; nt < 4; ++nt) {
    int c = wc + nt * 16 + l16;
    b1v[nt] = bd1[c];
    w2v[nt] = wd2[c];
  }
  __syncthreads();
  // fused epilogue: relu, scale by wd2, reduce over the 128 output cols
  for (int mt = 0; mt < 4; ++mt)
    for (int r = 0; r < 4; ++r) {
      float s = 0.0f;
      for (int nt = 0; nt < 4; ++nt) {
        float v = acc[mt][nt][r] + b1v[nt];
        v = fmaxf(v, 0.0f);
        s += v * w2v[nt];
      }
      // reduce across the 16 lanes holding cols of this row (xor 1,2,4,8 stay in quad)
      s += __shfl_xor(s, 1);
      s += __shfl_xor(s, 2);
      s += __shfl_xor(s, 4);
      s += __shfl_xor(s, 8);
      if (l16 == 0) atomicAdd(&osum[wr + mt * 16 + quad * 4 + r], s);
    }
  __syncthreads();
  if (tid < 128) out[base + tid] = osum[tid] + bd2[0];
}

// ---------------- host ----------------
extern "C" void kernel_launch(void* const* d_in, const int* in_sizes, int n_in,
                              void* d_out, int out_size, void* d_ws, size_t ws_size,
                              hipStream_t stream) {
  const float* x   = (const float*)d_in[0];
  const int*   ei  = (const int*)d_in[1];
  const float* W1l = (const float*)d_in[2];
  const float* b1l = (const float*)d_in[3];
  const float* W1r = (const float*)d_in[4];
  const float* W2l = (const float*)d_in[5];
  const float* b2l = (const float*)d_in[6];
  const float* W2r = (const float*)d_in[7];
  const float* Wd1 = (const float*)d_in[8];
  const float* bd1 = (const float*)d_in[9];
  const float* Wd2 = (const float*)d_in[10];
  const float* bd2 = (const float*)d_in[11];
  float* out = (float*)d_out;

  const int N = NN, E = NE;
  const int* srcv = ei;
  const int* dstv = ei + E;

  char* w = (char*)d_ws;
  size_t off = 0;
  auto take = [&](size_t bytes) {
    size_t o = off;
    off = (off + bytes + 255) & ~(size_t)255;
    return o;
  };
  int*  cnt    = (int*)(w + take((size_t)N * 4));
  int*  cursor = (int*)(w + take((size_t)N * 4));
  int*  rowptr = (int*)(w + take((size_t)(N + 1) * 4));
  int*  csr    = (int*)(w + take((size_t)E * 4));
  bf16* xb     = (bf16*)(w + take((size_t)N * 256 * 2));
  bf16* mean   = (bf16*)(w + take((size_t)N * 256 * 2));  // reused conv1 & conv2
  bf16* h      = (bf16*)(w + take((size_t)N * 256 * 2));
  bf16* zf     = (bf16*)(w + take((size_t)N * 128 * 2));
  bf16* B1     = (bf16*)(w + take((size_t)131072 * 2));
  bf16* B2     = (bf16*)(w + take((size_t)65536 * 2));
  bf16* Bd     = (bf16*)(w + take((size_t)32768 * 2));
  (void)ws_size; (void)n_in; (void)in_sizes; (void)out_size;

  // zero cnt + cursor (contiguous region)
  hipMemsetAsync(cnt, 0, (size_t)((char*)rowptr - (char*)cnt), stream);

  k_hist<<<E / 256, 256, 0, stream>>>(dstv, cnt, E);
  k_scan<<<1, 1024, 0, stream>>>(cnt, rowptr, N);
  k_fill<<<E / 256, 256, 0, stream>>>(srcv, dstv, rowptr, cursor, csr, E);
  k_cvt_x<<<(N * 256 / 4) / 256, 256, 0, stream>>>(x, xb);
  k_cvt_w<<<896, 256, 0, stream>>>(W1l, W1r, W2l, W2r, Wd1, B1, B2, Bd);

  // conv1: h = relu([mean|x] @ [W1l|W1r]^T + b1l)
  k_agg<<<N / 4, 256, 0, stream>>>(xb, rowptr, csr, mean);
  k_conv_gemm<256, true><<<dim3(782, 2), 256, 0, stream>>>(mean, xb, B1, b1l, h, N);
  // conv2: z = [mean2|h] @ [W2l|W2r]^T + b2l
  k_agg<<<N / 4, 256, 0, stream>>>(h, rowptr, csr, mean);
  k_conv_gemm<128, false><<<dim3(782, 1), 256, 0, stream>>>(mean, h, B2, b2l, zf, N);
  // decoder
  k_decoder<<<E / 128, 256, 0, stream>>>(zf, srcv, dstv, Bd, bd1, Wd2, bd2, out);
}

// Round 2
// 953.472 us; speedup vs baseline: 1.1801x; 1.1801x over previous
//
#include <hip/hip_runtime.h>
#include <stdint.h>

// GNNAutoEncoder: 2x SAGEConv(mean) + edge MLP decoder.
// N=100000 nodes, E=1600000 edges, D=256, HIDDEN=256, OUT=128.
static constexpr int NN = 100000;
static constexpr int NE = 1600000;

typedef __bf16 bf16;
typedef __bf16 bf16x4 __attribute__((ext_vector_type(4)));
typedef __bf16 bf16x8 __attribute__((ext_vector_type(8)));
typedef float floatx4 __attribute__((ext_vector_type(4)));

// async global->LDS, 16B per lane. LDS dest is wave-uniform base + lane*16.
__device__ __forceinline__ void async16(const void* g, void* l) {
  __builtin_amdgcn_global_load_lds(
      (const __attribute__((address_space(1))) void*)g,
      (__attribute__((address_space(3))) void*)l, 16, 0, 0);
}

// ---------------- CSR build ----------------
__global__ void k_hist(const int* __restrict__ dst, int* __restrict__ cnt, int E) {
  int e = blockIdx.x * 256 + threadIdx.x;
  if (e < E) atomicAdd(&cnt[dst[e]], 1);
}

__global__ __launch_bounds__(1024) void k_scan(const int* __restrict__ cnt,
                                               int* __restrict__ rowptr, int N) {
  __shared__ int sh[1024];
  int t = threadIdx.x;
  int chunk = (N + 1023) >> 10;
  int b = t * chunk;
  int e = b + chunk; if (e > N) e = N;
  int s = 0;
  for (int i = b; i < e; ++i) s += cnt[i];
  sh[t] = s;
  __syncthreads();
  for (int off = 1; off < 1024; off <<= 1) {
    int v = (t >= off) ? sh[t - off] : 0;
    __syncthreads();
    sh[t] += v;
    __syncthreads();
  }
  int run = sh[t] - s;  // exclusive prefix
  for (int i = b; i < e; ++i) { rowptr[i] = run; run += cnt[i]; }
  if (b < N && e == N) rowptr[N] = run;  // exactly one thread
}

__global__ void k_fill(const int* __restrict__ src, const int* __restrict__ dst,
                       const int* __restrict__ rowptr, int* __restrict__ cursor,
                       int* __restrict__ csr, int E) {
  int e = blockIdx.x * 256 + threadIdx.x;
  if (e < E) {
    int d = dst[e];
    int pos = rowptr[d] + atomicAdd(&cursor[d], 1);
    csr[pos] = src[e];
  }
}

// ---------------- dtype converts ----------------
__global__ void k_cvt_x(const float* __restrict__ x, bf16* __restrict__ xb) {
  int t = blockIdx.x * 256 + threadIdx.x;  // 4 elems / thread
  const float4 v = ((const float4*)x)[t];
  bf16x4 o;
  o.x = (bf16)v.x; o.y = (bf16)v.y; o.z = (bf16)v.z; o.w = (bf16)v.w;
  ((bf16x4*)xb)[t] = o;
}

// B1 = [W1l | W1r] as [256][512]; B2 = [W2l | W2r] as [128][512];
// Bd = [Wd1[:, :128] ; Wd1[:, 128:]] as [256][128]; biasPQ = [bd1 | 0] (256 f32).
__global__ void k_cvt_w(const float* __restrict__ W1l, const float* __restrict__ W1r,
                        const float* __restrict__ W2l, const float* __restrict__ W2r,
                        const float* __restrict__ Wd1, const float* __restrict__ bd1,
                        bf16* __restrict__ B1, bf16* __restrict__ B2,
                        bf16* __restrict__ Bd, float* __restrict__ biasPQ) {
  int g = blockIdx.x * 256 + threadIdx.x;  // 229632 total
  if (g < 131072) {
    int o = g >> 9, k = g & 511;
    float v = (k < 256) ? W1l[o * 256 + k] : W1r[o * 256 + k - 256];
    B1[g] = (bf16)v;
  } else if (g < 131072 + 65536) {
    int t = g - 131072;
    int o = t >> 9, k = t & 511;
    float v = (k < 256) ? W2l[o * 256 + k] : W2r[o * 256 + k - 256];
    B2[t] = (bf16)v;
  } else if (g < 131072 + 65536 + 32768) {
    int t = g - 196608;
    int o = t >> 7, k = t & 127;
    float v = (o < 128) ? Wd1[o * 256 + k] : Wd1[(o - 128) * 256 + 128 + k];
    Bd[t] = (bf16)v;
  } else if (g < 131072 + 65536 + 32768 + 256) {
    int t = g - 229376;
    biasPQ[t] = (t < 128) ? bd1[t] : 0.0f;
  }
}

// ---------------- mean aggregation (CSR gather) ----------------
// one wave per node; half-wave per source row, lane covers 8 cols (bf16x8).
__global__ void k_agg(const bf16* __restrict__ feat, const int* __restrict__ rowptr,
                      const int* __restrict__ csr, bf16* __restrict__ mean) {
  int wave = threadIdx.x >> 6, lane = threadIdx.x & 63;
  int n = blockIdx.x * 4 + wave;
  int s = rowptr[n], e = rowptr[n + 1];
  int half = lane >> 5, l32 = lane & 31;
  float a[8] = {};
  const bf16* base = feat + l32 * 8;
  for (int i = s + half; i < e; i += 2) {
    int sn = csr[i];
    bf16x8 v = *(const bf16x8*)(base + (size_t)sn * 256);
#pragma unroll
    for (int j = 0; j < 8; ++j) a[j] += (float)v[j];
  }
  int deg = e - s;
  float sc = 1.0f / (float)(deg > 0 ? deg : 1);
  bf16x8 o;
#pragma unroll
  for (int j = 0; j < 8; ++j) {
    float t = a[j] + __shfl_xor(a[j], 32);
    o[j] = (bf16)(t * sc);
  }
  if (half == 0)
    *(bf16x8*)(mean + (size_t)n * 256 + l32 * 8) = o;
}

// ---------------- SAGEConv GEMM: out = act([A1|A2] @ B^T + bias) ----------------
// A1,A2: bf16 [Nrows][256] each (K=512 concat). B: bf16 [NOUT_TOT][512].
// Tile BM=128 x BN=128, BK=64, 4 waves 2x2. XOR-swizzled LDS (seg^(row&7)).
template <int NOUT_TOT, bool RELU>
__global__ __launch_bounds__(256) void k_conv_gemm(
    const bf16* __restrict__ A1, const bf16* __restrict__ A2,
    const bf16* __restrict__ B, const float* __restrict__ bias,
    bf16* __restrict__ out, int Nrows) {
  __shared__ bf16 As[128 * 64];
  __shared__ bf16 Bs[128 * 64];
  const int tid = threadIdx.x, wave = tid >> 6, lane = tid & 63;
  const int quad = lane >> 4, l16 = lane & 15;
  const int rowBase = blockIdx.x * 128;
  const int colBase = blockIdx.y * 128;
  const int wr = (wave >> 1) * 64;
  const int wc = (wave & 1) * 64;
  floatx4 acc[4][4] = {};

  for (int kc = 0; kc < 8; ++kc) {
    const bf16* Asrc = (kc < 4) ? A1 : A2;
    const int kb = (kc & 3) * 64;
    for (int i = 0; i < 4; ++i) {
      int u = wave * 256 + i * 64 + lane;
      int row = u >> 3, seg = u & 7;
      int sg = seg ^ (row & 7);  // swizzled global seg -> LDS seg
      int node = rowBase + row;
      if (node >= Nrows) node = Nrows - 1;
      async16(Asrc + (size_t)node * 256 + kb + sg * 8, &As[(wave * 256 + i * 64) * 8]);
    }
    for (int i = 0; i < 4; ++i) {
      int u = wave * 256 + i * 64 + lane;
      int row = u >> 3, seg = u & 7;
      int sg = seg ^ (row & 7);
      async16(B + (size_t)(colBase + row) * 512 + kc * 64 + sg * 8,
              &Bs[(wave * 256 + i * 64) * 8]);
    }
    __syncthreads();
    for (int ks = 0; ks < 2; ++ks) {
      bf16x8 af[4], bq[4];
      const int sw = (ks * 4 + quad) ^ (l16 & 7);
      for (int mt = 0; mt < 4; ++mt)
        af[mt] = *(const bf16x8*)&As[(wr + mt * 16 + l16) * 64 + sw * 8];
      for (int nt = 0; nt < 4; ++nt)
        bq[nt] = *(const bf16x8*)&Bs[(wc + nt * 16 + l16) * 64 + sw * 8];
      for (int mt = 0; mt < 4; ++mt)
        for (int nt = 0; nt < 4; ++nt)
          acc[mt][nt] = __builtin_amdgcn_mfma_f32_16x16x32_bf16(af[mt], bq[nt], acc[mt][nt], 0, 0, 0);
    }
    __syncthreads();
  }
  float bv[4];
  for (int nt = 0; nt < 4; ++nt) bv[nt] = bias[colBase + wc + nt * 16 + l16];
  for (int mt = 0; mt < 4; ++mt)
    for (int nt = 0; nt < 4; ++nt) {
      int gcol = colBase + wc + nt * 16 + l16;
      for (int r = 0; r < 4; ++r) {
        int grow = rowBase + wr + mt * 16 + quad * 4 + r;
        if (grow < Nrows) {
          float v = acc[mt][nt][r] + bv[nt];
          if (RELU) v = fmaxf(v, 0.0f);
          out[(size_t)grow * NOUT_TOT + gcol] = (bf16)v;
        }
      }
    }
}

// ---------------- PQ GEMM: PQ = z @ Bd^T + biasPQ ----------------
// A: bf16 [Nrows][128], Bd: bf16 [256][128]. Output [Nrows][256] bf16.
__global__ __launch_bounds__(256) void k_pq_gemm(
    const bf16* __restrict__ A, const bf16* __restrict__ B,
    const float* __restrict__ bias, bf16* __restrict__ out, int Nrows) {
  __shared__ bf16 As[128 * 64];
  __shared__ bf16 Bs[128 * 64];
  const int tid = threadIdx.x, wave = tid >> 6, lane = tid & 63;
  const int quad = lane >> 4, l16 = lane & 15;
  const int rowBase = blockIdx.x * 128;
  const int colBase = blockIdx.y * 128;
  const int wr = (wave >> 1) * 64;
  const int wc = (wave & 1) * 64;
  floatx4 acc[4][4] = {};

  for (int kc = 0; kc < 2; ++kc) {
    for (int i = 0; i < 4; ++i) {
      int u = wave * 256 + i * 64 + lane;
      int row = u >> 3, seg = u & 7;
      int sg = seg ^ (row & 7);
      int node = rowBase + row;
      if (node >= Nrows) node = Nrows - 1;
      async16(A + (size_t)node * 128 + kc * 64 + sg * 8, &As[(wave * 256 + i * 64) * 8]);
    }
    for (int i = 0; i < 4; ++i) {
      int u = wave * 256 + i * 64 + lane;
      int row = u >> 3, seg = u & 7;
      int sg = seg ^ (row & 7);
      async16(B + (size_t)(colBase + row) * 128 + kc * 64 + sg * 8,
              &Bs[(wave * 256 + i * 64) * 8]);
    }
    __syncthreads();
    for (int ks = 0; ks < 2; ++ks) {
      bf16x8 af[4], bq[4];
      const int sw = (ks * 4 + quad) ^ (l16 & 7);
      for (int mt = 0; mt < 4; ++mt)
        af[mt] = *(const bf16x8*)&As[(wr + mt * 16 + l16) * 64 + sw * 8];
      for (int nt = 0; nt < 4; ++nt)
        bq[nt] = *(const bf16x8*)&Bs[(wc + nt * 16 + l16) * 64 + sw * 8];
      for (int mt = 0; mt < 4; ++mt)
        for (int nt = 0; nt < 4; ++nt)
          acc[mt][nt] = __builtin_amdgcn_mfma_f32_16x16x32_bf16(af[mt], bq[nt], acc[mt][nt], 0, 0, 0);
    }
    __syncthreads();
  }
  float bv[4];
  for (int nt = 0; nt < 4; ++nt) bv[nt] = bias[colBase + wc + nt * 16 + l16];
  for (int mt = 0; mt < 4; ++mt)
    for (int nt = 0; nt < 4; ++nt) {
      int gcol = colBase + wc + nt * 16 + l16;
      for (int r = 0; r < 4; ++r) {
        int grow = rowBase + wr + mt * 16 + quad * 4 + r;
        if (grow < Nrows)
          out[(size_t)grow * 256 + gcol] = (bf16)(acc[mt][nt][r] + bv[nt]);
      }
    }
}

// ---------------- edge kernel: out[e] = sum_o relu(P[s][o]+Q[d][o]) * wd2[o] + bd2 ----------------
// 16 lanes per edge; lane covers 8 of 128 outputs. PQ row: [P(128) | Q(128)] bf16.
__global__ __launch_bounds__(256) void k_edge(
    const bf16* __restrict__ PQ, const int* __restrict__ src, const int* __restrict__ dstv,
    const float* __restrict__ wd2, const float* __restrict__ bd2,
    float* __restrict__ out) {
  const int tid = threadIdx.x;
  const int g = tid >> 4, l = tid & 15;
  const int e = blockIdx.x * 16 + g;
  const int s = src[e], d = dstv[e];
  bf16x8 p = *(const bf16x8*)(PQ + (size_t)s * 256 + l * 8);
  bf16x8 q = *(const bf16x8*)(PQ + (size_t)d * 256 + 128 + l * 8);
  const float4* w4 = (const float4*)(wd2 + l * 8);
  float4 wa = w4[0], wb = w4[1];
  float w[8] = {wa.x, wa.y, wa.z, wa.w, wb.x, wb.y, wb.z, wb.w};
  float acc = 0.0f;
#pragma unroll
  for (int j = 0; j < 8; ++j) {
    float v = (float)p[j] + (float)q[j];
    acc += fmaxf(v, 0.0f) * w[j];
  }
  acc += __shfl_xor(acc, 1);
  acc += __shfl_xor(acc, 2);
  acc += __shfl_xor(acc, 4);
  acc += __shfl_xor(acc, 8);
  if (l == 0) out[e] = acc + bd2[0];
}

// ---------------- host ----------------
extern "C" void kernel_launch(void* const* d_in, const int* in_sizes, int n_in,
                              void* d_out, int out_size, void* d_ws, size_t ws_size,
                              hipStream_t stream) {
  const float* x   = (const float*)d_in[0];
  const int*   ei  = (const int*)d_in[1];
  const float* W1l = (const float*)d_in[2];
  const float* b1l = (const float*)d_in[3];
  const float* W1r = (const float*)d_in[4];
  const float* W2l = (const float*)d_in[5];
  const float* b2l = (const float*)d_in[6];
  const float* W2r = (const float*)d_in[7];
  const float* Wd1 = (const float*)d_in[8];
  const float* bd1 = (const float*)d_in[9];
  const float* Wd2 = (const float*)d_in[10];
  const float* bd2 = (const float*)d_in[11];
  float* out = (float*)d_out;

  const int N = NN, E = NE;
  const int* srcv = ei;
  const int* dstv = ei + E;

  char* w = (char*)d_ws;
  size_t off = 0;
  auto take = [&](size_t bytes) {
    size_t o = off;
    off = (off + bytes + 255) & ~(size_t)255;
    return o;
  };
  int*   cnt    = (int*)(w + take((size_t)N * 4));
  int*   cursor = (int*)(w + take((size_t)N * 4));
  int*   rowptr = (int*)(w + take((size_t)(N + 1) * 4));
  int*   csr    = (int*)(w + take((size_t)E * 4));
  bf16*  xb     = (bf16*)(w + take((size_t)N * 256 * 2));
  bf16*  mean   = (bf16*)(w + take((size_t)N * 256 * 2));  // reused: agg1, agg2, then PQ
  bf16*  h      = (bf16*)(w + take((size_t)N * 256 * 2));
  bf16*  zf     = (bf16*)(w + take((size_t)N * 128 * 2));
  bf16*  B1     = (bf16*)(w + take((size_t)131072 * 2));
  bf16*  B2     = (bf16*)(w + take((size_t)65536 * 2));
  bf16*  Bd     = (bf16*)(w + take((size_t)32768 * 2));
  float* biasPQ = (float*)(w + take((size_t)256 * 4));
  bf16*  PQ     = mean;  // mean dead after conv2; PQ written by k_pq_gemm
  (void)ws_size; (void)n_in; (void)in_sizes; (void)out_size;

  hipMemsetAsync(cnt, 0, (size_t)((char*)rowptr - (char*)cnt), stream);

  k_hist<<<E / 256, 256, 0, stream>>>(dstv, cnt, E);
  k_scan<<<1, 1024, 0, stream>>>(cnt, rowptr, N);
  k_fill<<<E / 256, 256, 0, stream>>>(srcv, dstv, rowptr, cursor, csr, E);
  k_cvt_x<<<(N * 256 / 4) / 256, 256, 0, stream>>>(x, xb);
  k_cvt_w<<<897, 256, 0, stream>>>(W1l, W1r, W2l, W2r, Wd1, bd1, B1, B2, Bd, biasPQ);

  // conv1: h = relu([mean|x] @ [W1l|W1r]^T + b1l)
  k_agg<<<N / 4, 256, 0, stream>>>(xb, rowptr, csr, mean);
  k_conv_gemm<256, true><<<dim3(782, 2), 256, 0, stream>>>(mean, xb, B1, b1l, h, N);
  // conv2: z = [mean2|h] @ [W2l|W2r]^T + b2l
  k_agg<<<N / 4, 256, 0, stream>>>(h, rowptr, csr, mean);
  k_conv_gemm<128, false><<<dim3(782, 1), 256, 0, stream>>>(mean, h, B2, b2l, zf, N);
  // decoder, node-level: PQ = zf @ Bd^T + [bd1|0]   (PQ aliases mean)
  k_pq_gemm<<<dim3(782, 2), 256, 0, stream>>>(zf, Bd, biasPQ, PQ, N);
  // decoder, edge-level
  k_edge<<<E / 16, 256, 0, stream>>>(PQ, srcv, dstv, Wd2, bd2, out);
}

// Round 3
// 742.859 us; speedup vs baseline: 1.5147x; 1.2835x over previous
//
#include <hip/hip_runtime.h>
#include <stdint.h>

// GNNAutoEncoder: 2x SAGEConv(mean) + edge MLP decoder.
// N=100000 nodes, E=1600000 edges, D=256, HIDDEN=256, OUT=128.
static constexpr int NN = 100000;
static constexpr int NE = 1600000;
static constexpr int NB_SCAN = (NN + 255) / 256;  // 391

typedef __bf16 bf16;
typedef __bf16 bf16x4 __attribute__((ext_vector_type(4)));
typedef __bf16 bf16x8 __attribute__((ext_vector_type(8)));
typedef float floatx4 __attribute__((ext_vector_type(4)));

// async global->LDS, 16B per lane. LDS dest is wave-uniform base + lane*16.
__device__ __forceinline__ void async16(const void* g, void* l) {
  __builtin_amdgcn_global_load_lds(
      (const __attribute__((address_space(1))) void*)g,
      (__attribute__((address_space(3))) void*)l, 16, 0, 0);
}

// ---------------- CSR build ----------------
__global__ void k_hist(const int* __restrict__ dst, int* __restrict__ cnt, int E) {
  int e = blockIdx.x * 256 + threadIdx.x;
  if (e < E) atomicAdd(&cnt[dst[e]], 1);
}

// hierarchical scan: partials -> scan partials -> local scan + offset
__global__ void k_scan_part(const int* __restrict__ cnt, int* __restrict__ part, int N) {
  __shared__ int sh[256];
  int t = threadIdx.x;
  int i = blockIdx.x * 256 + t;
  sh[t] = (i < N) ? cnt[i] : 0;
  __syncthreads();
  for (int off = 128; off > 0; off >>= 1) {
    if (t < off) sh[t] += sh[t + off];
    __syncthreads();
  }
  if (t == 0) part[blockIdx.x] = sh[0];
}

__global__ __launch_bounds__(512) void k_scan_mid(int* __restrict__ part, int NB) {
  __shared__ int sh[512];
  int t = threadIdx.x;
  int v = (t < NB) ? part[t] : 0;
  sh[t] = v;
  __syncthreads();
  for (int off = 1; off < 512; off <<= 1) {
    int u = (t >= off) ? sh[t - off] : 0;
    __syncthreads();
    sh[t] += u;
    __syncthreads();
  }
  if (t < NB) part[t] = sh[t] - v;  // exclusive
}

__global__ void k_scan_fin(const int* __restrict__ cnt, const int* __restrict__ part,
                           int* __restrict__ rowptr, int N, int E) {
  __shared__ int sh[256];
  int t = threadIdx.x;
  int i = blockIdx.x * 256 + t;
  int v = (i < N) ? cnt[i] : 0;
  sh[t] = v;
  __syncthreads();
  for (int off = 1; off < 256; off <<= 1) {
    int u = (t >= off) ? sh[t - off] : 0;
    __syncthreads();
    sh[t] += u;
    __syncthreads();
  }
  if (i < N) rowptr[i] = part[blockIdx.x] + sh[t] - v;  // exclusive prefix
  if (i == 0) rowptr[N] = E;
}

__global__ void k_fill(const int* __restrict__ src, const int* __restrict__ dst,
                       const int* __restrict__ rowptr, int* __restrict__ cursor,
                       int* __restrict__ csr, int E) {
  int e = blockIdx.x * 256 + threadIdx.x;
  if (e < E) {
    int d = dst[e];
    int pos = rowptr[d] + atomicAdd(&cursor[d], 1);
    csr[pos] = src[e];
  }
}

// ---------------- dtype converts ----------------
__global__ void k_cvt_x(const float* __restrict__ x, bf16* __restrict__ xb) {
  int t = blockIdx.x * 256 + threadIdx.x;  // 4 elems / thread
  const float4 v = ((const float4*)x)[t];
  bf16x4 o;
  o.x = (bf16)v.x; o.y = (bf16)v.y; o.z = (bf16)v.z; o.w = (bf16)v.w;
  ((bf16x4*)xb)[t] = o;
}

// B1 = [W1l | W1r] as [256][512]; B2 = [W2l ; W2r] stacked as [256][256];
// Bd = [Wd1[:, :128] ; Wd1[:, 128:]] as [256][128]; biasPQ = [bd1 | 0] (256 f32).
__global__ void k_cvt_w(const float* __restrict__ W1l, const float* __restrict__ W1r,
                        const float* __restrict__ W2l, const float* __restrict__ W2r,
                        const float* __restrict__ Wd1, const float* __restrict__ bd1,
                        bf16* __restrict__ B1, bf16* __restrict__ B2,
                        bf16* __restrict__ Bd, float* __restrict__ biasPQ) {
  int g = blockIdx.x * 256 + threadIdx.x;  // 229632 total
  if (g < 131072) {
    int o = g >> 9, k = g & 511;
    float v = (k < 256) ? W1l[o * 256 + k] : W1r[o * 256 + k - 256];
    B1[g] = (bf16)v;
  } else if (g < 131072 + 65536) {
    int t = g - 131072;
    int o = t >> 8, k = t & 255;
    float v = (o < 128) ? W2l[o * 256 + k] : W2r[(o - 128) * 256 + k];
    B2[t] = (bf16)v;
  } else if (g < 131072 + 65536 + 32768) {
    int t = g - 196608;
    int o = t >> 7, k = t & 127;
    float v = (o < 128) ? Wd1[o * 256 + k] : Wd1[(o - 128) * 256 + 128 + k];
    Bd[t] = (bf16)v;
  } else if (g < 131072 + 65536 + 32768 + 256) {
    int t = g - 229376;
    biasPQ[t] = (t < 128) ? bd1[t] : 0.0f;
  }
}

// ---------------- mean aggregation (CSR gather), 256-wide rows ----------------
// one wave per node; half-wave per source row, lane covers 8 cols (bf16x8).
__global__ void k_agg(const bf16* __restrict__ feat, const int* __restrict__ rowptr,
                      const int* __restrict__ csr, bf16* __restrict__ mean) {
  int wave = threadIdx.x >> 6, lane = threadIdx.x & 63;
  int n = blockIdx.x * 4 + wave;
  int s = rowptr[n], e = rowptr[n + 1];
  int half = lane >> 5, l32 = lane & 31;
  float a[8] = {};
  const bf16* base = feat + l32 * 8;
  for (int i = s + half; i < e; i += 2) {
    int sn = csr[i];
    bf16x8 v = *(const bf16x8*)(base + (size_t)sn * 256);
#pragma unroll
    for (int j = 0; j < 8; ++j) a[j] += (float)v[j];
  }
  int deg = e - s;
  float sc = 1.0f / (float)(deg > 0 ? deg : 1);
  bf16x8 o;
#pragma unroll
  for (int j = 0; j < 8; ++j) {
    float t = a[j] + __shfl_xor(a[j], 32);
    o[j] = (bf16)(t * sc);
  }
  if (half == 0)
    *(bf16x8*)(mean + (size_t)n * 256 + l32 * 8) = o;
}

// ---------------- layer-2 aggregate+combine ----------------
// hlr [N][256]: cols 0..127 = h@W2l^T, 128..255 = h@W2r^T.
// zf[n] = agg_mean(hl over neighbors) + hr[n] + b2l. Quarter-wave per row.
__global__ void k_agg2z(const bf16* __restrict__ hlr, const int* __restrict__ rowptr,
                        const int* __restrict__ csr, const float* __restrict__ b2l,
                        bf16* __restrict__ zf) {
  int wave = threadIdx.x >> 6, lane = threadIdx.x & 63;
  int n = blockIdx.x * 4 + wave;
  int s = rowptr[n], e = rowptr[n + 1];
  int sub = lane >> 4, l16 = lane & 15;
  float a[8] = {};
  const bf16* base = hlr + l16 * 8;  // hl half
  for (int i = s + sub; i < e; i += 4) {
    int sn = csr[i];
    bf16x8 v = *(const bf16x8*)(base + (size_t)sn * 256);
#pragma unroll
    for (int j = 0; j < 8; ++j) a[j] += (float)v[j];
  }
  int deg = e - s;
  float sc = 1.0f / (float)(deg > 0 ? deg : 1);
  bf16x8 hr = *(const bf16x8*)(hlr + (size_t)n * 256 + 128 + l16 * 8);
  const float4* b4 = (const float4*)(b2l + l16 * 8);
  float4 ba = b4[0], bb = b4[1];
  float bl[8] = {ba.x, ba.y, ba.z, ba.w, bb.x, bb.y, bb.z, bb.w};
  bf16x8 o;
#pragma unroll
  for (int j = 0; j < 8; ++j) {
    float t = a[j];
    t += __shfl_xor(t, 16);
    t += __shfl_xor(t, 32);
    o[j] = (bf16)(t * sc + (float)hr[j] + bl[j]);
  }
  if (sub == 0)
    *(bf16x8*)(zf + (size_t)n * 128 + l16 * 8) = o;
}

// ---------------- SAGEConv1 GEMM: out = relu([A1|A2] @ B^T + bias) ----------------
// A1,A2: bf16 [Nrows][256] each (K=512 concat). B: bf16 [256][512]. out [N][256].
__global__ __launch_bounds__(256) void k_conv_gemm(
    const bf16* __restrict__ A1, const bf16* __restrict__ A2,
    const bf16* __restrict__ B, const float* __restrict__ bias,
    bf16* __restrict__ out, int Nrows) {
  __shared__ bf16 As[128 * 64];
  __shared__ bf16 Bs[128 * 64];
  const int tid = threadIdx.x, wave = tid >> 6, lane = tid & 63;
  const int quad = lane >> 4, l16 = lane & 15;
  const int rowBase = blockIdx.x * 128;
  const int colBase = blockIdx.y * 128;
  const int wr = (wave >> 1) * 64;
  const int wc = (wave & 1) * 64;
  floatx4 acc[4][4] = {};

  for (int kc = 0; kc < 8; ++kc) {
    const bf16* Asrc = (kc < 4) ? A1 : A2;
    const int kb = (kc & 3) * 64;
    for (int i = 0; i < 4; ++i) {
      int u = wave * 256 + i * 64 + lane;
      int row = u >> 3, seg = u & 7;
      int sg = seg ^ (row & 7);  // swizzled global seg -> LDS seg
      int node = rowBase + row;
      if (node >= Nrows) node = Nrows - 1;
      async16(Asrc + (size_t)node * 256 + kb + sg * 8, &As[(wave * 256 + i * 64) * 8]);
    }
    for (int i = 0; i < 4; ++i) {
      int u = wave * 256 + i * 64 + lane;
      int row = u >> 3, seg = u & 7;
      int sg = seg ^ (row & 7);
      async16(B + (size_t)(colBase + row) * 512 + kc * 64 + sg * 8,
              &Bs[(wave * 256 + i * 64) * 8]);
    }
    __syncthreads();
    for (int ks = 0; ks < 2; ++ks) {
      bf16x8 af[4], bq[4];
      const int sw = (ks * 4 + quad) ^ (l16 & 7);
      for (int mt = 0; mt < 4; ++mt)
        af[mt] = *(const bf16x8*)&As[(wr + mt * 16 + l16) * 64 + sw * 8];
      for (int nt = 0; nt < 4; ++nt)
        bq[nt] = *(const bf16x8*)&Bs[(wc + nt * 16 + l16) * 64 + sw * 8];
      for (int mt = 0; mt < 4; ++mt)
        for (int nt = 0; nt < 4; ++nt)
          acc[mt][nt] = __builtin_amdgcn_mfma_f32_16x16x32_bf16(af[mt], bq[nt], acc[mt][nt], 0, 0, 0);
    }
    __syncthreads();
  }
  float bv[4];
  for (int nt = 0; nt < 4; ++nt) bv[nt] = bias[colBase + wc + nt * 16 + l16];
  for (int mt = 0; mt < 4; ++mt)
    for (int nt = 0; nt < 4; ++nt) {
      int gcol = colBase + wc + nt * 16 + l16;
      for (int r = 0; r < 4; ++r) {
        int grow = rowBase + wr + mt * 16 + quad * 4 + r;
        if (grow < Nrows) {
          float v = fmaxf(acc[mt][nt][r] + bv[nt], 0.0f);
          out[(size_t)grow * 256 + gcol] = (bf16)v;
        }
      }
    }
}

// ---------------- generic GEMM: out[N][256] = A[N][KDIM] @ B[256][KDIM]^T (+bias) ----------------
template <int KDIM, bool HASBIAS>
__global__ __launch_bounds__(256) void k_gemm(
    const bf16* __restrict__ A, const bf16* __restrict__ B,
    const float* __restrict__ bias, bf16* __restrict__ out, int Nrows) {
  __shared__ bf16 As[128 * 64];
  __shared__ bf16 Bs[128 * 64];
  const int tid = threadIdx.x, wave = tid >> 6, lane = tid & 63;
  const int quad = lane >> 4, l16 = lane & 15;
  const int rowBase = blockIdx.x * 128;
  const int colBase = blockIdx.y * 128;
  const int wr = (wave >> 1) * 64;
  const int wc = (wave & 1) * 64;
  floatx4 acc[4][4] = {};

  for (int kc = 0; kc < KDIM / 64; ++kc) {
    for (int i = 0; i < 4; ++i) {
      int u = wave * 256 + i * 64 + lane;
      int row = u >> 3, seg = u & 7;
      int sg = seg ^ (row & 7);
      int node = rowBase + row;
      if (node >= Nrows) node = Nrows - 1;
      async16(A + (size_t)node * KDIM + kc * 64 + sg * 8, &As[(wave * 256 + i * 64) * 8]);
    }
    for (int i = 0; i < 4; ++i) {
      int u = wave * 256 + i * 64 + lane;
      int row = u >> 3, seg = u & 7;
      int sg = seg ^ (row & 7);
      async16(B + (size_t)(colBase + row) * KDIM + kc * 64 + sg * 8,
              &Bs[(wave * 256 + i * 64) * 8]);
    }
    __syncthreads();
    for (int ks = 0; ks < 2; ++ks) {
      bf16x8 af[4], bq[4];
      const int sw = (ks * 4 + quad) ^ (l16 & 7);
      for (int mt = 0; mt < 4; ++mt)
        af[mt] = *(const bf16x8*)&As[(wr + mt * 16 + l16) * 64 + sw * 8];
      for (int nt = 0; nt < 4; ++nt)
        bq[nt] = *(const bf16x8*)&Bs[(wc + nt * 16 + l16) * 64 + sw * 8];
      for (int mt = 0; mt < 4; ++mt)
        for (int nt = 0; nt < 4; ++nt)
          acc[mt][nt] = __builtin_amdgcn_mfma_f32_16x16x32_bf16(af[mt], bq[nt], acc[mt][nt], 0, 0, 0);
    }
    __syncthreads();
  }
  float bv[4];
  for (int nt = 0; nt < 4; ++nt)
    bv[nt] = HASBIAS ? bias[colBase + wc + nt * 16 + l16] : 0.0f;
  for (int mt = 0; mt < 4; ++mt)
    for (int nt = 0; nt < 4; ++nt) {
      int gcol = colBase + wc + nt * 16 + l16;
      for (int r = 0; r < 4; ++r) {
        int grow = rowBase + wr + mt * 16 + quad * 4 + r;
        if (grow < Nrows)
          out[(size_t)grow * 256 + gcol] = (bf16)(acc[mt][nt][r] + bv[nt]);
      }
    }
}

// ---------------- edge kernel ----------------
// out[e] = sum_o relu(P[s][o]+Q[d][o]) * wd2[o] + bd2. 16 lanes/edge, 8 cols/lane.
__global__ __launch_bounds__(256) void k_edge(
    const bf16* __restrict__ PQ, const int* __restrict__ src, const int* __restrict__ dstv,
    const float* __restrict__ wd2, const float* __restrict__ bd2,
    float* __restrict__ out) {
  const int tid = threadIdx.x;
  const int g = tid >> 4, l = tid & 15;
  const int e = blockIdx.x * 16 + g;
  const int s = src[e], d = dstv[e];
  bf16x8 p = *(const bf16x8*)(PQ + (size_t)s * 256 + l * 8);
  bf16x8 q = *(const bf16x8*)(PQ + (size_t)d * 256 + 128 + l * 8);
  const float4* w4 = (const float4*)(wd2 + l * 8);
  float4 wa = w4[0], wb = w4[1];
  float w[8] = {wa.x, wa.y, wa.z, wa.w, wb.x, wb.y, wb.z, wb.w};
  float acc = 0.0f;
#pragma unroll
  for (int j = 0; j < 8; ++j) {
    float v = (float)p[j] + (float)q[j];
    acc += fmaxf(v, 0.0f) * w[j];
  }
  acc += __shfl_xor(acc, 1);
  acc += __shfl_xor(acc, 2);
  acc += __shfl_xor(acc, 4);
  acc += __shfl_xor(acc, 8);
  if (l == 0) out[e] = acc + bd2[0];
}

// ---------------- host ----------------
extern "C" void kernel_launch(void* const* d_in, const int* in_sizes, int n_in,
                              void* d_out, int out_size, void* d_ws, size_t ws_size,
                              hipStream_t stream) {
  const float* x   = (const float*)d_in[0];
  const int*   ei  = (const int*)d_in[1];
  const float* W1l = (const float*)d_in[2];
  const float* b1l = (const float*)d_in[3];
  const float* W1r = (const float*)d_in[4];
  const float* W2l = (const float*)d_in[5];
  const float* b2l = (const float*)d_in[6];
  const float* W2r = (const float*)d_in[7];
  const float* Wd1 = (const float*)d_in[8];
  const float* bd1 = (const float*)d_in[9];
  const float* Wd2 = (const float*)d_in[10];
  const float* bd2 = (const float*)d_in[11];
  float* out = (float*)d_out;

  const int N = NN, E = NE;
  const int* srcv = ei;
  const int* dstv = ei + E;

  char* w = (char*)d_ws;
  size_t off = 0;
  auto take = [&](size_t bytes) {
    size_t o = off;
    off = (off + bytes + 255) & ~(size_t)255;
    return o;
  };
  int*   cnt    = (int*)(w + take((size_t)N * 4));
  int*   cursor = (int*)(w + take((size_t)N * 4));
  int*   rowptr = (int*)(w + take((size_t)(N + 1) * 4));
  int*   part   = (int*)(w + take((size_t)NB_SCAN * 4));
  int*   csr    = (int*)(w + take((size_t)E * 4));
  bf16*  xb     = (bf16*)(w + take((size_t)N * 256 * 2));
  bf16*  mean   = (bf16*)(w + take((size_t)N * 256 * 2));  // reused: agg1, hlr, PQ
  bf16*  h      = (bf16*)(w + take((size_t)N * 256 * 2));
  bf16*  zf     = (bf16*)(w + take((size_t)N * 128 * 2));
  bf16*  B1     = (bf16*)(w + take((size_t)131072 * 2));
  bf16*  B2     = (bf16*)(w + take((size_t)65536 * 2));
  bf16*  Bd     = (bf16*)(w + take((size_t)32768 * 2));
  float* biasPQ = (float*)(w + take((size_t)256 * 4));
  bf16*  hlr    = mean;  // mean dead after conv1 GEMM
  bf16*  PQ     = mean;  // hlr dead after k_agg2z
  (void)ws_size; (void)n_in; (void)in_sizes; (void)out_size;

  hipMemsetAsync(cnt, 0, (size_t)((char*)rowptr - (char*)cnt), stream);

  k_hist<<<E / 256, 256, 0, stream>>>(dstv, cnt, E);
  k_scan_part<<<NB_SCAN, 256, 0, stream>>>(cnt, part, N);
  k_scan_mid<<<1, 512, 0, stream>>>(part, NB_SCAN);
  k_scan_fin<<<NB_SCAN, 256, 0, stream>>>(cnt, part, rowptr, N, E);
  k_fill<<<E / 256, 256, 0, stream>>>(srcv, dstv, rowptr, cursor, csr, E);
  k_cvt_x<<<(N * 256 / 4) / 256, 256, 0, stream>>>(x, xb);
  k_cvt_w<<<897, 256, 0, stream>>>(W1l, W1r, W2l, W2r, Wd1, bd1, B1, B2, Bd, biasPQ);

  // conv1: h = relu([mean|x] @ [W1l|W1r]^T + b1l)
  k_agg<<<N / 4, 256, 0, stream>>>(xb, rowptr, csr, mean);
  k_conv_gemm<<<dim3(782, 2), 256, 0, stream>>>(mean, xb, B1, b1l, h, N);
  // conv2 (transform-then-aggregate): hlr = h @ [W2l;W2r]^T, then
  // zf = agg_mean(hl) + hr + b2l
  k_gemm<256, false><<<dim3(782, 2), 256, 0, stream>>>(h, B2, nullptr, hlr, N);
  k_agg2z<<<N / 4, 256, 0, stream>>>(hlr, rowptr, csr, b2l, zf);
  // decoder, node-level: PQ = zf @ Bd^T + [bd1|0]
  k_gemm<128, true><<<dim3(782, 2), 256, 0, stream>>>(zf, Bd, biasPQ, PQ, N);
  // decoder, edge-level
  k_edge<<<E / 16, 256, 0, stream>>>(PQ, srcv, dstv, Wd2, bd2, out);
}

// Round 4
// 725.951 us; speedup vs baseline: 1.5500x; 1.0233x over previous
//
#include <hip/hip_runtime.h>
#include <stdint.h>

// GNNAutoEncoder: 2x SAGEConv(mean) + edge MLP decoder.
// N=100000 nodes, E=1600000 edges, D=256, HIDDEN=256, OUT=128.
static constexpr int NN = 100000;
static constexpr int NE = 1600000;
static constexpr int NB_SCAN = (NN + 255) / 256;  // 391
static constexpr int NB_CVTX = NN * 256 / 4 / 256;  // 25000
static constexpr int NB_HIST = NE / 256;            // 6250
static constexpr int NB_CVTW = 897;

typedef __bf16 bf16;
typedef __bf16 bf16x4 __attribute__((ext_vector_type(4)));
typedef __bf16 bf16x8 __attribute__((ext_vector_type(8)));
typedef float floatx4 __attribute__((ext_vector_type(4)));

// async global->LDS, 16B per lane. LDS dest is wave-uniform base + lane*16.
__device__ __forceinline__ void async16(const void* g, void* l) {
  __builtin_amdgcn_global_load_lds(
      (const __attribute__((address_space(1))) void*)g,
      (__attribute__((address_space(3))) void*)l, 16, 0, 0);
}

// ---------------- fused: x->bf16 convert | dst histogram ----------------
__global__ void k_cvtx_hist(const float* __restrict__ x, bf16* __restrict__ xb,
                            const int* __restrict__ dst, int* __restrict__ cnt) {
  int b = blockIdx.x;
  if (b < NB_CVTX) {
    int t = b * 256 + threadIdx.x;  // 4 elems / thread
    const float4 v = ((const float4*)x)[t];
    bf16x4 o;
    o.x = (bf16)v.x; o.y = (bf16)v.y; o.z = (bf16)v.z; o.w = (bf16)v.w;
    ((bf16x4*)xb)[t] = o;
  } else {
    int e = (b - NB_CVTX) * 256 + threadIdx.x;
    atomicAdd(&cnt[dst[e]], 1);
  }
}

// ---------------- fused: weight packs | scan partials ----------------
// B1 = [W1l | W1r] as [256][512]; B2 = [W2l ; W2r] stacked as [256][256];
// Bd = [Wd1[:, :128] ; Wd1[:, 128:]] as [256][128]; biasPQ = [bd1 | 0] (256 f32).
__global__ void k_cvtw_scanpart(
    const float* __restrict__ W1l, const float* __restrict__ W1r,
    const float* __restrict__ W2l, const float* __restrict__ W2r,
    const float* __restrict__ Wd1, const float* __restrict__ bd1,
    bf16* __restrict__ B1, bf16* __restrict__ B2,
    bf16* __restrict__ Bd, float* __restrict__ biasPQ,
    const int* __restrict__ cnt, int* __restrict__ part, int N) {
  int b = blockIdx.x;
  if (b < NB_CVTW) {
    int g = b * 256 + threadIdx.x;  // 229632 total
    if (g < 131072) {
      int o = g >> 9, k = g & 511;
      float v = (k < 256) ? W1l[o * 256 + k] : W1r[o * 256 + k - 256];
      B1[g] = (bf16)v;
    } else if (g < 131072 + 65536) {
      int t = g - 131072;
      int o = t >> 8, k = t & 255;
      float v = (o < 128) ? W2l[o * 256 + k] : W2r[(o - 128) * 256 + k];
      B2[t] = (bf16)v;
    } else if (g < 131072 + 65536 + 32768) {
      int t = g - 196608;
      int o = t >> 7, k = t & 127;
      float v = (o < 128) ? Wd1[o * 256 + k] : Wd1[(o - 128) * 256 + 128 + k];
      Bd[t] = (bf16)v;
    } else if (g < 131072 + 65536 + 32768 + 256) {
      int t = g - 229376;
      biasPQ[t] = (t < 128) ? bd1[t] : 0.0f;
    }
  } else {
    __shared__ int sh[256];
    int bb = b - NB_CVTW;
    int t = threadIdx.x;
    int i = bb * 256 + t;
    sh[t] = (i < N) ? cnt[i] : 0;
    __syncthreads();
    for (int off = 128; off > 0; off >>= 1) {
      if (t < off) sh[t] += sh[t + off];
      __syncthreads();
    }
    if (t == 0) part[bb] = sh[0];
  }
}

__global__ __launch_bounds__(512) void k_scan_mid(int* __restrict__ part, int NB) {
  __shared__ int sh[512];
  int t = threadIdx.x;
  int v = (t < NB) ? part[t] : 0;
  sh[t] = v;
  __syncthreads();
  for (int off = 1; off < 512; off <<= 1) {
    int u = (t >= off) ? sh[t - off] : 0;
    __syncthreads();
    sh[t] += u;
    __syncthreads();
  }
  if (t < NB) part[t] = sh[t] - v;  // exclusive
}

__global__ void k_scan_fin(const int* __restrict__ cnt, const int* __restrict__ part,
                           int* __restrict__ rowptr, int N, int E) {
  __shared__ int sh[256];
  int t = threadIdx.x;
  int i = blockIdx.x * 256 + t;
  int v = (i < N) ? cnt[i] : 0;
  sh[t] = v;
  __syncthreads();
  for (int off = 1; off < 256; off <<= 1) {
    int u = (t >= off) ? sh[t - off] : 0;
    __syncthreads();
    sh[t] += u;
    __syncthreads();
  }
  if (i < N) rowptr[i] = part[blockIdx.x] + sh[t] - v;  // exclusive prefix
  if (i == 0) rowptr[N] = E;
}

__global__ void k_fill(const int* __restrict__ src, const int* __restrict__ dst,
                       const int* __restrict__ rowptr, int* __restrict__ cursor,
                       int* __restrict__ csr, int E) {
  int e = blockIdx.x * 256 + threadIdx.x;
  if (e < E) {
    int d = dst[e];
    int pos = rowptr[d] + atomicAdd(&cursor[d], 1);
    csr[pos] = src[e];
  }
}

// ---------------- mean aggregation (CSR gather), 256-wide rows ----------------
// one wave per node; half-wave per source row, lane covers 8 cols (bf16x8).
// 4-deep software pipeline: 4 independent row gathers in flight per half-wave.
__global__ void k_agg(const bf16* __restrict__ feat, const int* __restrict__ rowptr,
                      const int* __restrict__ csr, bf16* __restrict__ mean) {
  int wave = threadIdx.x >> 6, lane = threadIdx.x & 63;
  int n = blockIdx.x * 4 + wave;
  int s = rowptr[n], e = rowptr[n + 1];
  int half = lane >> 5, l32 = lane & 31;
  float a[8] = {};
  const bf16* base = feat + l32 * 8;
  int i = s + half;
  for (; i + 6 < e; i += 8) {
    int c0 = csr[i], c1 = csr[i + 2], c2 = csr[i + 4], c3 = csr[i + 6];
    bf16x8 v0 = *(const bf16x8*)(base + (size_t)c0 * 256);
    bf16x8 v1 = *(const bf16x8*)(base + (size_t)c1 * 256);
    bf16x8 v2 = *(const bf16x8*)(base + (size_t)c2 * 256);
    bf16x8 v3 = *(const bf16x8*)(base + (size_t)c3 * 256);
#pragma unroll
    for (int j = 0; j < 8; ++j)
      a[j] += ((float)v0[j] + (float)v1[j]) + ((float)v2[j] + (float)v3[j]);
  }
  for (; i < e; i += 2) {
    int c = csr[i];
    bf16x8 v = *(const bf16x8*)(base + (size_t)c * 256);
#pragma unroll
    for (int j = 0; j < 8; ++j) a[j] += (float)v[j];
  }
  int deg = e - s;
  float sc = 1.0f / (float)(deg > 0 ? deg : 1);
  bf16x8 o;
#pragma unroll
  for (int j = 0; j < 8; ++j) {
    float t = a[j] + __shfl_xor(a[j], 32);
    o[j] = (bf16)(t * sc);
  }
  if (half == 0)
    *(bf16x8*)(mean + (size_t)n * 256 + l32 * 8) = o;
}

// ---------------- layer-2 aggregate+combine ----------------
// hlr [N][256]: cols 0..127 = h@W2l^T, 128..255 = h@W2r^T.
// zf[n] = agg_mean(hl over neighbors) + hr[n] + b2l. Quarter-wave per row,
// 2-deep pipeline (8 rows in flight per wave).
__global__ void k_agg2z(const bf16* __restrict__ hlr, const int* __restrict__ rowptr,
                        const int* __restrict__ csr, const float* __restrict__ b2l,
                        bf16* __restrict__ zf) {
  int wave = threadIdx.x >> 6, lane = threadIdx.x & 63;
  int n = blockIdx.x * 4 + wave;
  int s = rowptr[n], e = rowptr[n + 1];
  int sub = lane >> 4, l16 = lane & 15;
  float a[8] = {};
  const bf16* base = hlr + l16 * 8;  // hl half
  int i = s + sub;
  for (; i + 4 < e; i += 8) {
    int c0 = csr[i], c1 = csr[i + 4];
    bf16x8 v0 = *(const bf16x8*)(base + (size_t)c0 * 256);
    bf16x8 v1 = *(const bf16x8*)(base + (size_t)c1 * 256);
#pragma unroll
    for (int j = 0; j < 8; ++j) a[j] += (float)v0[j] + (float)v1[j];
  }
  for (; i < e; i += 4) {
    int c = csr[i];
    bf16x8 v = *(const bf16x8*)(base + (size_t)c * 256);
#pragma unroll
    for (int j = 0; j < 8; ++j) a[j] += (float)v[j];
  }
  int deg = e - s;
  float sc = 1.0f / (float)(deg > 0 ? deg : 1);
  bf16x8 hr = *(const bf16x8*)(hlr + (size_t)n * 256 + 128 + l16 * 8);
  const float4* b4 = (const float4*)(b2l + l16 * 8);
  float4 ba = b4[0], bb = b4[1];
  float bl[8] = {ba.x, ba.y, ba.z, ba.w, bb.x, bb.y, bb.z, bb.w};
  bf16x8 o;
#pragma unroll
  for (int j = 0; j < 8; ++j) {
    float t = a[j];
    t += __shfl_xor(t, 16);
    t += __shfl_xor(t, 32);
    o[j] = (bf16)(t * sc + (float)hr[j] + bl[j]);
  }
  if (sub == 0)
    *(bf16x8*)(zf + (size_t)n * 128 + l16 * 8) = o;
}

// ---------------- SAGEConv1 GEMM: out = relu([A1|A2] @ B^T + bias) ----------------
// A1,A2: bf16 [Nrows][256] each (K=512 concat). B: bf16 [256][512]. out [N][256].
__global__ __launch_bounds__(256) void k_conv_gemm(
    const bf16* __restrict__ A1, const bf16* __restrict__ A2,
    const bf16* __restrict__ B, const float* __restrict__ bias,
    bf16* __restrict__ out, int Nrows) {
  __shared__ bf16 As[128 * 64];
  __shared__ bf16 Bs[128 * 64];
  const int tid = threadIdx.x, wave = tid >> 6, lane = tid & 63;
  const int quad = lane >> 4, l16 = lane & 15;
  const int rowBase = blockIdx.x * 128;
  const int colBase = blockIdx.y * 128;
  const int wr = (wave >> 1) * 64;
  const int wc = (wave & 1) * 64;
  floatx4 acc[4][4] = {};

  for (int kc = 0; kc < 8; ++kc) {
    const bf16* Asrc = (kc < 4) ? A1 : A2;
    const int kb = (kc & 3) * 64;
    for (int i = 0; i < 4; ++i) {
      int u = wave * 256 + i * 64 + lane;
      int row = u >> 3, seg = u & 7;
      int sg = seg ^ (row & 7);  // swizzled global seg -> LDS seg
      int node = rowBase + row;
      if (node >= Nrows) node = Nrows - 1;
      async16(Asrc + (size_t)node * 256 + kb + sg * 8, &As[(wave * 256 + i * 64) * 8]);
    }
    for (int i = 0; i < 4; ++i) {
      int u = wave * 256 + i * 64 + lane;
      int row = u >> 3, seg = u & 7;
      int sg = seg ^ (row & 7);
      async16(B + (size_t)(colBase + row) * 512 + kc * 64 + sg * 8,
              &Bs[(wave * 256 + i * 64) * 8]);
    }
    __syncthreads();
    for (int ks = 0; ks < 2; ++ks) {
      bf16x8 af[4], bq[4];
      const int sw = (ks * 4 + quad) ^ (l16 & 7);
      for (int mt = 0; mt < 4; ++mt)
        af[mt] = *(const bf16x8*)&As[(wr + mt * 16 + l16) * 64 + sw * 8];
      for (int nt = 0; nt < 4; ++nt)
        bq[nt] = *(const bf16x8*)&Bs[(wc + nt * 16 + l16) * 64 + sw * 8];
      for (int mt = 0; mt < 4; ++mt)
        for (int nt = 0; nt < 4; ++nt)
          acc[mt][nt] = __builtin_amdgcn_mfma_f32_16x16x32_bf16(af[mt], bq[nt], acc[mt][nt], 0, 0, 0);
    }
    __syncthreads();
  }
  float bv[4];
  for (int nt = 0; nt < 4; ++nt) bv[nt] = bias[colBase + wc + nt * 16 + l16];
  for (int mt = 0; mt < 4; ++mt)
    for (int nt = 0; nt < 4; ++nt) {
      int gcol = colBase + wc + nt * 16 + l16;
      for (int r = 0; r < 4; ++r) {
        int grow = rowBase + wr + mt * 16 + quad * 4 + r;
        if (grow < Nrows) {
          float v = fmaxf(acc[mt][nt][r] + bv[nt], 0.0f);
          out[(size_t)grow * 256 + gcol] = (bf16)v;
        }
      }
    }
}

// ---------------- generic GEMM: out[N][256] = A[N][KDIM] @ B[256][KDIM]^T (+bias) ----------------
template <int KDIM, bool HASBIAS>
__global__ __launch_bounds__(256) void k_gemm(
    const bf16* __restrict__ A, const bf16* __restrict__ B,
    const float* __restrict__ bias, bf16* __restrict__ out, int Nrows) {
  __shared__ bf16 As[128 * 64];
  __shared__ bf16 Bs[128 * 64];
  const int tid = threadIdx.x, wave = tid >> 6, lane = tid & 63;
  const int quad = lane >> 4, l16 = lane & 15;
  const int rowBase = blockIdx.x * 128;
  const int colBase = blockIdx.y * 128;
  const int wr = (wave >> 1) * 64;
  const int wc = (wave & 1) * 64;
  floatx4 acc[4][4] = {};

  for (int kc = 0; kc < KDIM / 64; ++kc) {
    for (int i = 0; i < 4; ++i) {
      int u = wave * 256 + i * 64 + lane;
      int row = u >> 3, seg = u & 7;
      int sg = seg ^ (row & 7);
      int node = rowBase + row;
      if (node >= Nrows) node = Nrows - 1;
      async16(A + (size_t)node * KDIM + kc * 64 + sg * 8, &As[(wave * 256 + i * 64) * 8]);
    }
    for (int i = 0; i < 4; ++i) {
      int u = wave * 256 + i * 64 + lane;
      int row = u >> 3, seg = u & 7;
      int sg = seg ^ (row & 7);
      async16(B + (size_t)(colBase + row) * KDIM + kc * 64 + sg * 8,
              &Bs[(wave * 256 + i * 64) * 8]);
    }
    __syncthreads();
    for (int ks = 0; ks < 2; ++ks) {
      bf16x8 af[4], bq[4];
      const int sw = (ks * 4 + quad) ^ (l16 & 7);
      for (int mt = 0; mt < 4; ++mt)
        af[mt] = *(const bf16x8*)&As[(wr + mt * 16 + l16) * 64 + sw * 8];
      for (int nt = 0; nt < 4; ++nt)
        bq[nt] = *(const bf16x8*)&Bs[(wc + nt * 16 + l16) * 64 + sw * 8];
      for (int mt = 0; mt < 4; ++mt)
        for (int nt = 0; nt < 4; ++nt)
          acc[mt][nt] = __builtin_amdgcn_mfma_f32_16x16x32_bf16(af[mt], bq[nt], acc[mt][nt], 0, 0, 0);
    }
    __syncthreads();
  }
  float bv[4];
  for (int nt = 0; nt < 4; ++nt)
    bv[nt] = HASBIAS ? bias[colBase + wc + nt * 16 + l16] : 0.0f;
  for (int mt = 0; mt < 4; ++mt)
    for (int nt = 0; nt < 4; ++nt) {
      int gcol = colBase + wc + nt * 16 + l16;
      for (int r = 0; r < 4; ++r) {
        int grow = rowBase + wr + mt * 16 + quad * 4 + r;
        if (grow < Nrows)
          out[(size_t)grow * 256 + gcol] = (bf16)(acc[mt][nt][r] + bv[nt]);
      }
    }
}

// ---------------- edge kernel ----------------
// out[e] = sum_o relu(P[s][o]+Q[d][o]) * wd2[o] + bd2. 16 lanes/edge, 8 cols/lane.
__global__ __launch_bounds__(256) void k_edge(
    const bf16* __restrict__ PQ, const int* __restrict__ src, const int* __restrict__ dstv,
    const float* __restrict__ wd2, const float* __restrict__ bd2,
    float* __restrict__ out) {
  const int tid = threadIdx.x;
  const int g = tid >> 4, l = tid & 15;
  const int e = blockIdx.x * 16 + g;
  const int s = src[e], d = dstv[e];
  bf16x8 p = *(const bf16x8*)(PQ + (size_t)s * 256 + l * 8);
  bf16x8 q = *(const bf16x8*)(PQ + (size_t)d * 256 + 128 + l * 8);
  const float4* w4 = (const float4*)(wd2 + l * 8);
  float4 wa = w4[0], wb = w4[1];
  float w[8] = {wa.x, wa.y, wa.z, wa.w, wb.x, wb.y, wb.z, wb.w};
  float acc = 0.0f;
#pragma unroll
  for (int j = 0; j < 8; ++j) {
    float v = (float)p[j] + (float)q[j];
    acc += fmaxf(v, 0.0f) * w[j];
  }
  acc += __shfl_xor(acc, 1);
  acc += __shfl_xor(acc, 2);
  acc += __shfl_xor(acc, 4);
  acc += __shfl_xor(acc, 8);
  if (l == 0) out[e] = acc + bd2[0];
}

// ---------------- host ----------------
extern "C" void kernel_launch(void* const* d_in, const int* in_sizes, int n_in,
                              void* d_out, int out_size, void* d_ws, size_t ws_size,
                              hipStream_t stream) {
  const float* x   = (const float*)d_in[0];
  const int*   ei  = (const int*)d_in[1];
  const float* W1l = (const float*)d_in[2];
  const float* b1l = (const float*)d_in[3];
  const float* W1r = (const float*)d_in[4];
  const float* W2l = (const float*)d_in[5];
  const float* b2l = (const float*)d_in[6];
  const float* W2r = (const float*)d_in[7];
  const float* Wd1 = (const float*)d_in[8];
  const float* bd1 = (const float*)d_in[9];
  const float* Wd2 = (const float*)d_in[10];
  const float* bd2 = (const float*)d_in[11];
  float* out = (float*)d_out;

  const int N = NN, E = NE;
  const int* srcv = ei;
  const int* dstv = ei + E;

  char* w = (char*)d_ws;
  size_t off = 0;
  auto take = [&](size_t bytes) {
    size_t o = off;
    off = (off + bytes + 255) & ~(size_t)255;
    return o;
  };
  int*   cnt    = (int*)(w + take((size_t)N * 4));
  int*   cursor = (int*)(w + take((size_t)N * 4));
  int*   rowptr = (int*)(w + take((size_t)(N + 1) * 4));
  int*   part   = (int*)(w + take((size_t)NB_SCAN * 4));
  int*   csr    = (int*)(w + take((size_t)E * 4));
  bf16*  xb     = (bf16*)(w + take((size_t)N * 256 * 2));
  bf16*  mean   = (bf16*)(w + take((size_t)N * 256 * 2));  // reused: agg1, hlr, PQ
  bf16*  h      = (bf16*)(w + take((size_t)N * 256 * 2));
  bf16*  zf     = (bf16*)(w + take((size_t)N * 128 * 2));
  bf16*  B1     = (bf16*)(w + take((size_t)131072 * 2));
  bf16*  B2     = (bf16*)(w + take((size_t)65536 * 2));
  bf16*  Bd     = (bf16*)(w + take((size_t)32768 * 2));
  float* biasPQ = (float*)(w + take((size_t)256 * 4));
  bf16*  hlr    = mean;  // mean dead after conv1 GEMM
  bf16*  PQ     = mean;  // hlr dead after k_agg2z
  (void)ws_size; (void)n_in; (void)in_sizes; (void)out_size;

  hipMemsetAsync(cnt, 0, (size_t)((char*)rowptr - (char*)cnt), stream);

  k_cvtx_hist<<<NB_CVTX + NB_HIST, 256, 0, stream>>>(x, xb, dstv, cnt);
  k_cvtw_scanpart<<<NB_CVTW + NB_SCAN, 256, 0, stream>>>(
      W1l, W1r, W2l, W2r, Wd1, bd1, B1, B2, Bd, biasPQ, cnt, part, N);
  k_scan_mid<<<1, 512, 0, stream>>>(part, NB_SCAN);
  k_scan_fin<<<NB_SCAN, 256, 0, stream>>>(cnt, part, rowptr, N, E);
  k_fill<<<E / 256, 256, 0, stream>>>(srcv, dstv, rowptr, cursor, csr, E);

  // conv1: h = relu([mean|x] @ [W1l|W1r]^T + b1l)
  k_agg<<<N / 4, 256, 0, stream>>>(xb, rowptr, csr, mean);
  k_conv_gemm<<<dim3(782, 2), 256, 0, stream>>>(mean, xb, B1, b1l, h, N);
  // conv2 (transform-then-aggregate): hlr = h @ [W2l;W2r]^T, then
  // zf = agg_mean(hl) + hr + b2l
  k_gemm<256, false><<<dim3(782, 2), 256, 0, stream>>>(h, B2, nullptr, hlr, N);
  k_agg2z<<<N / 4, 256, 0, stream>>>(hlr, rowptr, csr, b2l, zf);
  // decoder, node-level: PQ = zf @ Bd^T + [bd1|0]
  k_gemm<128, true><<<dim3(782, 2), 256, 0, stream>>>(zf, Bd, biasPQ, PQ, N);
  // decoder, edge-level
  k_edge<<<E / 16, 256, 0, stream>>>(PQ, srcv, dstv, Wd2, bd2, out);
}

// Round 5
// 666.607 us; speedup vs baseline: 1.6879x; 1.0890x over previous
//
#include <hip/hip_runtime.h>
#include <stdint.h>

// GNNAutoEncoder: 2x SAGEConv(mean) + edge MLP decoder.
// N=100000 nodes, E=1600000 edges, D=256, HIDDEN=256, OUT=128.
static constexpr int NN = 100000;
static constexpr int NE = 1600000;
static constexpr int NB_SCAN = (NN + 255) / 256;  // 391
static constexpr int NB_CVTX = NN * 256 / 4 / 256;  // 25000
static constexpr int NB_HIST = NE / 256;            // 6250
static constexpr int NB_CVTW = 897;

typedef __bf16 bf16;
typedef __bf16 bf16x4 __attribute__((ext_vector_type(4)));
typedef __bf16 bf16x8 __attribute__((ext_vector_type(8)));
typedef float floatx4 __attribute__((ext_vector_type(4)));

// async global->LDS, 16B per lane. LDS dest is wave-uniform base + lane*16.
__device__ __forceinline__ void async16(const void* g, void* l) {
  __builtin_amdgcn_global_load_lds(
      (const __attribute__((address_space(1))) void*)g,
      (__attribute__((address_space(3))) void*)l, 16, 0, 0);
}

// pack 4 floats -> 4 OCP e4m3 bytes
__device__ __forceinline__ uint32_t pk4_fp8(float a, float b, float c, float d) {
  uint32_t v = 0;
  v = (uint32_t)__builtin_amdgcn_cvt_pk_fp8_f32(a, b, (int)v, false);
  v = (uint32_t)__builtin_amdgcn_cvt_pk_fp8_f32(c, d, (int)v, true);
  return v;
}

// accumulate 8 fp8 (uint2) into float[8]
__device__ __forceinline__ void acc_fp8x8(float* a, uint2 v) {
  a[0] += __builtin_amdgcn_cvt_f32_fp8(v.x, 0);
  a[1] += __builtin_amdgcn_cvt_f32_fp8(v.x, 1);
  a[2] += __builtin_amdgcn_cvt_f32_fp8(v.x, 2);
  a[3] += __builtin_amdgcn_cvt_f32_fp8(v.x, 3);
  a[4] += __builtin_amdgcn_cvt_f32_fp8(v.y, 0);
  a[5] += __builtin_amdgcn_cvt_f32_fp8(v.y, 1);
  a[6] += __builtin_amdgcn_cvt_f32_fp8(v.y, 2);
  a[7] += __builtin_amdgcn_cvt_f32_fp8(v.y, 3);
}

// ---------------- fused: x->bf16+fp8 convert | dst histogram ----------------
__global__ void k_cvtx_hist(const float* __restrict__ x, bf16* __restrict__ xb,
                            uint32_t* __restrict__ xq,
                            const int* __restrict__ dst, int* __restrict__ cnt) {
  int b = blockIdx.x;
  if (b < NB_CVTX) {
    int t = b * 256 + threadIdx.x;  // 4 elems / thread
    const float4 v = ((const float4*)x)[t];
    bf16x4 o;
    o.x = (bf16)v.x; o.y = (bf16)v.y; o.z = (bf16)v.z; o.w = (bf16)v.w;
    ((bf16x4*)xb)[t] = o;
    xq[t] = pk4_fp8(v.x, v.y, v.z, v.w);
  } else {
    int e = (b - NB_CVTX) * 256 + threadIdx.x;
    atomicAdd(&cnt[dst[e]], 1);
  }
}

// ---------------- fused: weight packs | scan partials ----------------
// B1 = [W1l | W1r] as [256][512]; B2 = [W2l ; W2r] stacked as [256][256];
// Bd = [Wd1[:, :128] ; Wd1[:, 128:]] as [256][128]; biasPQ = [bd1 | 0] (256 f32).
__global__ void k_cvtw_scanpart(
    const float* __restrict__ W1l, const float* __restrict__ W1r,
    const float* __restrict__ W2l, const float* __restrict__ W2r,
    const float* __restrict__ Wd1, const float* __restrict__ bd1,
    bf16* __restrict__ B1, bf16* __restrict__ B2,
    bf16* __restrict__ Bd, float* __restrict__ biasPQ,
    const int* __restrict__ cnt, int* __restrict__ part, int N) {
  int b = blockIdx.x;
  if (b < NB_CVTW) {
    int g = b * 256 + threadIdx.x;  // 229632 total
    if (g < 131072) {
      int o = g >> 9, k = g & 511;
      float v = (k < 256) ? W1l[o * 256 + k] : W1r[o * 256 + k - 256];
      B1[g] = (bf16)v;
    } else if (g < 131072 + 65536) {
      int t = g - 131072;
      int o = t >> 8, k = t & 255;
      float v = (o < 128) ? W2l[o * 256 + k] : W2r[(o - 128) * 256 + k];
      B2[t] = (bf16)v;
    } else if (g < 131072 + 65536 + 32768) {
      int t = g - 196608;
      int o = t >> 7, k = t & 127;
      float v = (o < 128) ? Wd1[o * 256 + k] : Wd1[(o - 128) * 256 + 128 + k];
      Bd[t] = (bf16)v;
    } else if (g < 131072 + 65536 + 32768 + 256) {
      int t = g - 229376;
      biasPQ[t] = (t < 128) ? bd1[t] : 0.0f;
    }
  } else {
    __shared__ int sh[256];
    int bb = b - NB_CVTW;
    int t = threadIdx.x;
    int i = bb * 256 + t;
    sh[t] = (i < N) ? cnt[i] : 0;
    __syncthreads();
    for (int off = 128; off > 0; off >>= 1) {
      if (t < off) sh[t] += sh[t + off];
      __syncthreads();
    }
    if (t == 0) part[bb] = sh[0];
  }
}

__global__ __launch_bounds__(512) void k_scan_mid(int* __restrict__ part, int NB) {
  __shared__ int sh[512];
  int t = threadIdx.x;
  int v = (t < NB) ? part[t] : 0;
  sh[t] = v;
  __syncthreads();
  for (int off = 1; off < 512; off <<= 1) {
    int u = (t >= off) ? sh[t - off] : 0;
    __syncthreads();
    sh[t] += u;
    __syncthreads();
  }
  if (t < NB) part[t] = sh[t] - v;  // exclusive
}

__global__ void k_scan_fin(const int* __restrict__ cnt, const int* __restrict__ part,
                           int* __restrict__ rowptr, int N, int E) {
  __shared__ int sh[256];
  int t = threadIdx.x;
  int i = blockIdx.x * 256 + t;
  int v = (i < N) ? cnt[i] : 0;
  sh[t] = v;
  __syncthreads();
  for (int off = 1; off < 256; off <<= 1) {
    int u = (t >= off) ? sh[t - off] : 0;
    __syncthreads();
    sh[t] += u;
    __syncthreads();
  }
  if (i < N) rowptr[i] = part[blockIdx.x] + sh[t] - v;  // exclusive prefix
  if (i == 0) rowptr[N] = E;
}

__global__ void k_fill(const int* __restrict__ src, const int* __restrict__ dst,
                       const int* __restrict__ rowptr, int* __restrict__ cursor,
                       int* __restrict__ csr, int* __restrict__ ceid, int E) {
  int e = blockIdx.x * 256 + threadIdx.x;
  if (e < E) {
    int d = dst[e];
    int pos = rowptr[d] + atomicAdd(&cursor[d], 1);
    csr[pos] = src[e];
    ceid[pos] = e;
  }
}

// ---------------- layer-1 mean aggregation (fp8 gather, 256 cols) ----------------
// one wave per node; half-wave per source row (32 lanes x 8B), 4-deep pipeline.
__global__ void k_agg(const uint8_t* __restrict__ xq, const int* __restrict__ rowptr,
                      const int* __restrict__ csr, bf16* __restrict__ mean) {
  int wave = threadIdx.x >> 6, lane = threadIdx.x & 63;
  int n = blockIdx.x * 4 + wave;
  int s = rowptr[n], e = rowptr[n + 1];
  int half = lane >> 5, l32 = lane & 31;
  float a[8] = {};
  const uint8_t* base = xq + l32 * 8;
  int i = s + half;
  for (; i + 6 < e; i += 8) {
    int c0 = csr[i], c1 = csr[i + 2], c2 = csr[i + 4], c3 = csr[i + 6];
    uint2 v0 = *(const uint2*)(base + (size_t)c0 * 256);
    uint2 v1 = *(const uint2*)(base + (size_t)c1 * 256);
    uint2 v2 = *(const uint2*)(base + (size_t)c2 * 256);
    uint2 v3 = *(const uint2*)(base + (size_t)c3 * 256);
    acc_fp8x8(a, v0); acc_fp8x8(a, v1); acc_fp8x8(a, v2); acc_fp8x8(a, v3);
  }
  for (; i < e; i += 2) {
    uint2 v = *(const uint2*)(base + (size_t)csr[i] * 256);
    acc_fp8x8(a, v);
  }
  int deg = e - s;
  float sc = 1.0f / (float)(deg > 0 ? deg : 1);
  bf16x8 o;
#pragma unroll
  for (int j = 0; j < 8; ++j) {
    float t = a[j] + __shfl_xor(a[j], 32);
    o[j] = (bf16)(t * sc);
  }
  if (half == 0)
    *(bf16x8*)(mean + (size_t)n * 256 + l32 * 8) = o;
}

// ---------------- layer-2 aggregate+combine (fp8 hl gather, 128 cols) ----------------
// zf[n] = agg_mean(hq over neighbors) + hr[n] + b2l. Quarter-wave per row,
// 2-deep pipeline.
__global__ void k_agg2z(const uint8_t* __restrict__ hq, const bf16* __restrict__ hr,
                        const int* __restrict__ rowptr, const int* __restrict__ csr,
                        const float* __restrict__ b2l, bf16* __restrict__ zf) {
  int wave = threadIdx.x >> 6, lane = threadIdx.x & 63;
  int n = blockIdx.x * 4 + wave;
  int s = rowptr[n], e = rowptr[n + 1];
  int sub = lane >> 4, l16 = lane & 15;
  float a[8] = {};
  const uint8_t* base = hq + l16 * 8;
  int i = s + sub;
  for (; i + 4 < e; i += 8) {
    int c0 = csr[i], c1 = csr[i + 4];
    uint2 v0 = *(const uint2*)(base + (size_t)c0 * 128);
    uint2 v1 = *(const uint2*)(base + (size_t)c1 * 128);
    acc_fp8x8(a, v0); acc_fp8x8(a, v1);
  }
  for (; i < e; i += 4) {
    uint2 v = *(const uint2*)(base + (size_t)csr[i] * 128);
    acc_fp8x8(a, v);
  }
  int deg = e - s;
  float sc = 1.0f / (float)(deg > 0 ? deg : 1);
  bf16x8 hv = *(const bf16x8*)(hr + (size_t)n * 128 + l16 * 8);
  const float4* b4 = (const float4*)(b2l + l16 * 8);
  float4 ba = b4[0], bb = b4[1];
  float bl[8] = {ba.x, ba.y, ba.z, ba.w, bb.x, bb.y, bb.z, bb.w};
  bf16x8 o;
#pragma unroll
  for (int j = 0; j < 8; ++j) {
    float t = a[j];
    t += __shfl_xor(t, 16);
    t += __shfl_xor(t, 32);
    o[j] = (bf16)(t * sc + (float)hv[j] + bl[j]);
  }
  if (sub == 0)
    *(bf16x8*)(zf + (size_t)n * 128 + l16 * 8) = o;
}

// ---------------- SAGEConv1 GEMM: h = relu([mean|x] @ B1^T + b1l) ----------------
// grid (2, 782): col-tile fastest for twin-block A reuse.
__global__ __launch_bounds__(256) void k_conv_gemm(
    const bf16* __restrict__ A1, const bf16* __restrict__ A2,
    const bf16* __restrict__ B, const float* __restrict__ bias,
    bf16* __restrict__ out, int Nrows) {
  __shared__ bf16 As[128 * 64];
  __shared__ bf16 Bs[128 * 64];
  const int tid = threadIdx.x, wave = tid >> 6, lane = tid & 63;
  const int quad = lane >> 4, l16 = lane & 15;
  const int rowBase = blockIdx.y * 128;
  const int colBase = blockIdx.x * 128;
  const int wr = (wave >> 1) * 64;
  const int wc = (wave & 1) * 64;
  floatx4 acc[4][4] = {};

  for (int kc = 0; kc < 8; ++kc) {
    const bf16* Asrc = (kc < 4) ? A1 : A2;
    const int kb = (kc & 3) * 64;
    for (int i = 0; i < 4; ++i) {
      int u = wave * 256 + i * 64 + lane;
      int row = u >> 3, seg = u & 7;
      int sg = seg ^ (row & 7);  // swizzled global seg -> LDS seg
      int node = rowBase + row;
      if (node >= Nrows) node = Nrows - 1;
      async16(Asrc + (size_t)node * 256 + kb + sg * 8, &As[(wave * 256 + i * 64) * 8]);
    }
    for (int i = 0; i < 4; ++i) {
      int u = wave * 256 + i * 64 + lane;
      int row = u >> 3, seg = u & 7;
      int sg = seg ^ (row & 7);
      async16(B + (size_t)(colBase + row) * 512 + kc * 64 + sg * 8,
              &Bs[(wave * 256 + i * 64) * 8]);
    }
    __syncthreads();
    for (int ks = 0; ks < 2; ++ks) {
      bf16x8 af[4], bq[4];
      const int sw = (ks * 4 + quad) ^ (l16 & 7);
      for (int mt = 0; mt < 4; ++mt)
        af[mt] = *(const bf16x8*)&As[(wr + mt * 16 + l16) * 64 + sw * 8];
      for (int nt = 0; nt < 4; ++nt)
        bq[nt] = *(const bf16x8*)&Bs[(wc + nt * 16 + l16) * 64 + sw * 8];
      for (int mt = 0; mt < 4; ++mt)
        for (int nt = 0; nt < 4; ++nt)
          acc[mt][nt] = __builtin_amdgcn_mfma_f32_16x16x32_bf16(af[mt], bq[nt], acc[mt][nt], 0, 0, 0);
    }
    __syncthreads();
  }
  float bv[4];
  for (int nt = 0; nt < 4; ++nt) bv[nt] = bias[colBase + wc + nt * 16 + l16];
  for (int mt = 0; mt < 4; ++mt)
    for (int nt = 0; nt < 4; ++nt) {
      int gcol = colBase + wc + nt * 16 + l16;
      for (int r = 0; r < 4; ++r) {
        int grow = rowBase + wr + mt * 16 + quad * 4 + r;
        if (grow < Nrows) {
          float v = fmaxf(acc[mt][nt][r] + bv[nt], 0.0f);
          out[(size_t)grow * 256 + gcol] = (bf16)v;
        }
      }
    }
}

// ---------------- generic GEMM with split epilogue ----------------
// out = A[N][KDIM] @ B[256][KDIM]^T (+bias). 256 output cols split:
// EPI=1: cols<128 -> fp8 out1 [N][128], cols>=128 -> bf16 out2 [N][128] (no bias)
// EPI=2: cols<128 -> bf16 out1 (+bias), cols>=128 -> bf16 out2 (+bias)
template <int KDIM, int EPI>
__global__ __launch_bounds__(256) void k_gemm(
    const bf16* __restrict__ A, const bf16* __restrict__ B,
    const float* __restrict__ bias, void* __restrict__ out1,
    void* __restrict__ out2, int Nrows) {
  __shared__ bf16 As[128 * 64];
  __shared__ bf16 Bs[128 * 64];
  const int tid = threadIdx.x, wave = tid >> 6, lane = tid & 63;
  const int quad = lane >> 4, l16 = lane & 15;
  const int rowBase = blockIdx.y * 128;
  const int colBase = blockIdx.x * 128;
  const int wr = (wave >> 1) * 64;
  const int wc = (wave & 1) * 64;
  floatx4 acc[4][4] = {};

  for (int kc = 0; kc < KDIM / 64; ++kc) {
    for (int i = 0; i < 4; ++i) {
      int u = wave * 256 + i * 64 + lane;
      int row = u >> 3, seg = u & 7;
      int sg = seg ^ (row & 7);
      int node = rowBase + row;
      if (node >= Nrows) node = Nrows - 1;
      async16(A + (size_t)node * KDIM + kc * 64 + sg * 8, &As[(wave * 256 + i * 64) * 8]);
    }
    for (int i = 0; i < 4; ++i) {
      int u = wave * 256 + i * 64 + lane;
      int row = u >> 3, seg = u & 7;
      int sg = seg ^ (row & 7);
      async16(B + (size_t)(colBase + row) * KDIM + kc * 64 + sg * 8,
              &Bs[(wave * 256 + i * 64) * 8]);
    }
    __syncthreads();
    for (int ks = 0; ks < 2; ++ks) {
      bf16x8 af[4], bq[4];
      const int sw = (ks * 4 + quad) ^ (l16 & 7);
      for (int mt = 0; mt < 4; ++mt)
        af[mt] = *(const bf16x8*)&As[(wr + mt * 16 + l16) * 64 + sw * 8];
      for (int nt = 0; nt < 4; ++nt)
        bq[nt] = *(const bf16x8*)&Bs[(wc + nt * 16 + l16) * 64 + sw * 8];
      for (int mt = 0; mt < 4; ++mt)
        for (int nt = 0; nt < 4; ++nt)
          acc[mt][nt] = __builtin_amdgcn_mfma_f32_16x16x32_bf16(af[mt], bq[nt], acc[mt][nt], 0, 0, 0);
    }
    __syncthreads();
  }
  float bv[4];
  for (int nt = 0; nt < 4; ++nt)
    bv[nt] = (EPI == 2) ? bias[colBase + wc + nt * 16 + l16] : 0.0f;
  const bool lowHalf = (colBase == 0);  // 256-col output, tile 0 = cols<128
  for (int mt = 0; mt < 4; ++mt)
    for (int nt = 0; nt < 4; ++nt) {
      int gcol = colBase + wc + nt * 16 + l16;
      for (int r = 0; r < 4; ++r) {
        int grow = rowBase + wr + mt * 16 + quad * 4 + r;
        if (grow < Nrows) {
          float v = acc[mt][nt][r] + bv[nt];
          if (lowHalf) {
            if (EPI == 1) {
              uint32_t pk = (uint32_t)__builtin_amdgcn_cvt_pk_fp8_f32(v, v, 0, false);
              ((uint8_t*)out1)[(size_t)grow * 128 + gcol] = (uint8_t)pk;
            } else {
              ((bf16*)out1)[(size_t)grow * 128 + gcol] = (bf16)v;
            }
          } else {
            ((bf16*)out2)[(size_t)grow * 128 + gcol - 128] = (bf16)v;
          }
        }
      }
    }
}

// ---------------- edge decoder, CSR-ordered ----------------
// out[eid] = sum_o relu(P[src][o]+Q[d][o]) * wd2[o] + bd2.
// one wave per dst node; quarter-wave (16 lanes x 8 cols) per edge.
__global__ __launch_bounds__(256) void k_edge(
    const bf16* __restrict__ P, const bf16* __restrict__ Q,
    const int* __restrict__ rowptr, const int* __restrict__ csr,
    const int* __restrict__ ceid,
    const float* __restrict__ wd2, const float* __restrict__ bd2,
    float* __restrict__ out) {
  int wave = threadIdx.x >> 6, lane = threadIdx.x & 63;
  int n = blockIdx.x * 4 + wave;
  int s = rowptr[n], e = rowptr[n + 1];
  int sub = lane >> 4, l16 = lane & 15;
  bf16x8 qv = *(const bf16x8*)(Q + (size_t)n * 128 + l16 * 8);
  float qf[8];
#pragma unroll
  for (int j = 0; j < 8; ++j) qf[j] = (float)qv[j];
  const float4* w4 = (const float4*)(wd2 + l16 * 8);
  float4 wa = w4[0], wb = w4[1];
  float w[8] = {wa.x, wa.y, wa.z, wa.w, wb.x, wb.y, wb.z, wb.w};
  const float bout = bd2[0];
  int i = s + sub;
  for (; i + 4 < e; i += 8) {
    int c0 = csr[i], e0 = ceid[i];
    int c1 = csr[i + 4], e1 = ceid[i + 4];
    bf16x8 p0 = *(const bf16x8*)(P + (size_t)c0 * 128 + l16 * 8);
    bf16x8 p1 = *(const bf16x8*)(P + (size_t)c1 * 128 + l16 * 8);
    float a0 = 0.f, a1 = 0.f;
#pragma unroll
    for (int j = 0; j < 8; ++j) {
      a0 += fmaxf((float)p0[j] + qf[j], 0.f) * w[j];
      a1 += fmaxf((float)p1[j] + qf[j], 0.f) * w[j];
    }
    a0 += __shfl_xor(a0, 1); a1 += __shfl_xor(a1, 1);
    a0 += __shfl_xor(a0, 2); a1 += __shfl_xor(a1, 2);
    a0 += __shfl_xor(a0, 4); a1 += __shfl_xor(a1, 4);
    a0 += __shfl_xor(a0, 8); a1 += __shfl_xor(a1, 8);
    if (l16 == 0) { out[e0] = a0 + bout; out[e1] = a1 + bout; }
  }
  for (; i < e; i += 4) {
    int c = csr[i], eid = ceid[i];
    bf16x8 p = *(const bf16x8*)(P + (size_t)c * 128 + l16 * 8);
    float a = 0.f;
#pragma unroll
    for (int j = 0; j < 8; ++j)
      a += fmaxf((float)p[j] + qf[j], 0.f) * w[j];
    a += __shfl_xor(a, 1);
    a += __shfl_xor(a, 2);
    a += __shfl_xor(a, 4);
    a += __shfl_xor(a, 8);
    if (l16 == 0) out[eid] = a + bout;
  }
}

// ---------------- host ----------------
extern "C" void kernel_launch(void* const* d_in, const int* in_sizes, int n_in,
                              void* d_out, int out_size, void* d_ws, size_t ws_size,
                              hipStream_t stream) {
  const float* x   = (const float*)d_in[0];
  const int*   ei  = (const int*)d_in[1];
  const float* W1l = (const float*)d_in[2];
  const float* b1l = (const float*)d_in[3];
  const float* W1r = (const float*)d_in[4];
  const float* W2l = (const float*)d_in[5];
  const float* b2l = (const float*)d_in[6];
  const float* W2r = (const float*)d_in[7];
  const float* Wd1 = (const float*)d_in[8];
  const float* bd1 = (const float*)d_in[9];
  const float* Wd2 = (const float*)d_in[10];
  const float* bd2 = (const float*)d_in[11];
  float* out = (float*)d_out;

  const int N = NN, E = NE;
  const int* srcv = ei;
  const int* dstv = ei + E;

  char* w = (char*)d_ws;
  size_t off = 0;
  auto take = [&](size_t bytes) {
    size_t o = off;
    off = (off + bytes + 255) & ~(size_t)255;
    return o;
  };
  int*      cnt    = (int*)(w + take((size_t)N * 4));
  int*      cursor = (int*)(w + take((size_t)N * 4));
  int*      rowptr = (int*)(w + take((size_t)(N + 1) * 4));
  int*      part   = (int*)(w + take((size_t)NB_SCAN * 4));
  int*      csr    = (int*)(w + take((size_t)E * 4));
  int*      ceid   = (int*)(w + take((size_t)E * 4));
  bf16*     xb     = (bf16*)(w + take((size_t)N * 256 * 2));
  uint8_t*  xq     = (uint8_t*)(w + take((size_t)N * 256));
  bf16*     mean   = (bf16*)(w + take((size_t)N * 256 * 2));  // reused: hq+hr
  bf16*     h      = (bf16*)(w + take((size_t)N * 256 * 2));  // reused: P+Q
  bf16*     zf     = (bf16*)(w + take((size_t)N * 128 * 2));
  bf16*     B1     = (bf16*)(w + take((size_t)131072 * 2));
  bf16*     B2     = (bf16*)(w + take((size_t)65536 * 2));
  bf16*     Bd     = (bf16*)(w + take((size_t)32768 * 2));
  float*    biasPQ = (float*)(w + take((size_t)256 * 4));
  // aliases (producer/consumer ordering makes these safe):
  uint8_t* hq = (uint8_t*)mean;                 // [N][128] fp8, after conv1
  bf16*    hr = (bf16*)(hq + (size_t)N * 128);  // [N][128] bf16
  bf16*    P  = h;                              // [N][128] bf16, after gemm256
  bf16*    Q  = h + (size_t)N * 128;            // [N][128] bf16
  (void)ws_size; (void)n_in; (void)in_sizes; (void)out_size;

  hipMemsetAsync(cnt, 0, (size_t)((char*)rowptr - (char*)cnt), stream);

  k_cvtx_hist<<<NB_CVTX + NB_HIST, 256, 0, stream>>>(x, xb, (uint32_t*)xq, dstv, cnt);
  k_cvtw_scanpart<<<NB_CVTW + NB_SCAN, 256, 0, stream>>>(
      W1l, W1r, W2l, W2r, Wd1, bd1, B1, B2, Bd, biasPQ, cnt, part, N);
  k_scan_mid<<<1, 512, 0, stream>>>(part, NB_SCAN);
  k_scan_fin<<<NB_SCAN, 256, 0, stream>>>(cnt, part, rowptr, N, E);
  k_fill<<<E / 256, 256, 0, stream>>>(srcv, dstv, rowptr, cursor, csr, ceid, E);

  // conv1: h = relu([mean|x] @ [W1l|W1r]^T + b1l)
  k_agg<<<N / 4, 256, 0, stream>>>(xq, rowptr, csr, mean);
  k_conv_gemm<<<dim3(2, 782), 256, 0, stream>>>(mean, xb, B1, b1l, h, N);
  // conv2 (transform-then-aggregate): [hq|hr] = h @ [W2l;W2r]^T (hq fp8),
  // then zf = agg_mean(hq) + hr + b2l
  k_gemm<256, 1><<<dim3(2, 782), 256, 0, stream>>>(h, B2, nullptr, hq, hr, N);
  k_agg2z<<<N / 4, 256, 0, stream>>>(hq, hr, rowptr, csr, b2l, zf);
  // decoder node-level: [P|Q] = zf @ Bd^T + [bd1|0]
  k_gemm<128, 2><<<dim3(2, 782), 256, 0, stream>>>(zf, Bd, biasPQ, P, Q, N);
  // decoder edge-level, CSR-ordered (Q dense per node, P gathered)
  k_edge<<<N / 4, 256, 0, stream>>>(P, Q, rowptr, csr, ceid, Wd2, bd2, out);
}

// Round 6
// 660.269 us; speedup vs baseline: 1.7042x; 1.0096x over previous
//
#include <hip/hip_runtime.h>
#include <stdint.h>

// GNNAutoEncoder: 2x SAGEConv(mean) + edge MLP decoder.
// N=100000 nodes, E=1600000 edges, D=256, HIDDEN=256, OUT=128.
static constexpr int NN = 100000;
static constexpr int NE = 1600000;
static constexpr int NB_SCAN = (NN + 255) / 256;  // 391
static constexpr int NB_CVTX = NN * 256 / 4 / 256;  // 25000
static constexpr int NB_HIST = NE / 256;            // 6250
static constexpr int NB_CVTW = 897;

typedef __bf16 bf16;
typedef __bf16 bf16x4 __attribute__((ext_vector_type(4)));
typedef __bf16 bf16x8 __attribute__((ext_vector_type(8)));
typedef float floatx4 __attribute__((ext_vector_type(4)));

// async global->LDS, 16B per lane. LDS dest is wave-uniform base + lane*16.
__device__ __forceinline__ void async16(const void* g, void* l) {
  __builtin_amdgcn_global_load_lds(
      (const __attribute__((address_space(1))) void*)g,
      (__attribute__((address_space(3))) void*)l, 16, 0, 0);
}

// pack 4 floats -> 4 OCP e4m3 bytes
__device__ __forceinline__ uint32_t pk4_fp8(float a, float b, float c, float d) {
  uint32_t v = 0;
  v = (uint32_t)__builtin_amdgcn_cvt_pk_fp8_f32(a, b, (int)v, false);
  v = (uint32_t)__builtin_amdgcn_cvt_pk_fp8_f32(c, d, (int)v, true);
  return v;
}

// accumulate 8 fp8 (uint2) into float[8]
__device__ __forceinline__ void acc_fp8x8(float* a, uint2 v) {
  a[0] += __builtin_amdgcn_cvt_f32_fp8(v.x, 0);
  a[1] += __builtin_amdgcn_cvt_f32_fp8(v.x, 1);
  a[2] += __builtin_amdgcn_cvt_f32_fp8(v.x, 2);
  a[3] += __builtin_amdgcn_cvt_f32_fp8(v.x, 3);
  a[4] += __builtin_amdgcn_cvt_f32_fp8(v.y, 0);
  a[5] += __builtin_amdgcn_cvt_f32_fp8(v.y, 1);
  a[6] += __builtin_amdgcn_cvt_f32_fp8(v.y, 2);
  a[7] += __builtin_amdgcn_cvt_f32_fp8(v.y, 3);
}

// ---------------- fused: x->bf16+fp8 convert | dst histogram ----------------
__global__ void k_cvtx_hist(const float* __restrict__ x, bf16* __restrict__ xb,
                            uint32_t* __restrict__ xq,
                            const int* __restrict__ dst, int* __restrict__ cnt) {
  int b = blockIdx.x;
  if (b < NB_CVTX) {
    int t = b * 256 + threadIdx.x;  // 4 elems / thread
    const float4 v = ((const float4*)x)[t];
    bf16x4 o;
    o.x = (bf16)v.x; o.y = (bf16)v.y; o.z = (bf16)v.z; o.w = (bf16)v.w;
    ((bf16x4*)xb)[t] = o;
    xq[t] = pk4_fp8(v.x, v.y, v.z, v.w);
  } else {
    int e = (b - NB_CVTX) * 256 + threadIdx.x;
    atomicAdd(&cnt[dst[e]], 1);
  }
}

// ---------------- fused: weight packs | scan partials ----------------
// B1 = [W1l | W1r] as [256][512]; B2 = [W2l ; W2r] stacked as [256][256];
// Bd = [Wd1[:, :128] ; Wd1[:, 128:]] as [256][128]; biasPQ = [bd1 | 0] (256 f32).
__global__ void k_cvtw_scanpart(
    const float* __restrict__ W1l, const float* __restrict__ W1r,
    const float* __restrict__ W2l, const float* __restrict__ W2r,
    const float* __restrict__ Wd1, const float* __restrict__ bd1,
    bf16* __restrict__ B1, bf16* __restrict__ B2,
    bf16* __restrict__ Bd, float* __restrict__ biasPQ,
    const int* __restrict__ cnt, int* __restrict__ part, int N) {
  int b = blockIdx.x;
  if (b < NB_CVTW) {
    int g = b * 256 + threadIdx.x;  // 229632 total
    if (g < 131072) {
      int o = g >> 9, k = g & 511;
      float v = (k < 256) ? W1l[o * 256 + k] : W1r[o * 256 + k - 256];
      B1[g] = (bf16)v;
    } else if (g < 131072 + 65536) {
      int t = g - 131072;
      int o = t >> 8, k = t & 255;
      float v = (o < 128) ? W2l[o * 256 + k] : W2r[(o - 128) * 256 + k];
      B2[t] = (bf16)v;
    } else if (g < 131072 + 65536 + 32768) {
      int t = g - 196608;
      int o = t >> 7, k = t & 127;
      float v = (o < 128) ? Wd1[o * 256 + k] : Wd1[(o - 128) * 256 + 128 + k];
      Bd[t] = (bf16)v;
    } else if (g < 131072 + 65536 + 32768 + 256) {
      int t = g - 229376;
      biasPQ[t] = (t < 128) ? bd1[t] : 0.0f;
    }
  } else {
    __shared__ int sh[256];
    int bb = b - NB_CVTW;
    int t = threadIdx.x;
    int i = bb * 256 + t;
    sh[t] = (i < N) ? cnt[i] : 0;
    __syncthreads();
    for (int off = 128; off > 0; off >>= 1) {
      if (t < off) sh[t] += sh[t + off];
      __syncthreads();
    }
    if (t == 0) part[bb] = sh[0];
  }
}

__global__ __launch_bounds__(512) void k_scan_mid(int* __restrict__ part, int NB) {
  __shared__ int sh[512];
  int t = threadIdx.x;
  int v = (t < NB) ? part[t] : 0;
  sh[t] = v;
  __syncthreads();
  for (int off = 1; off < 512; off <<= 1) {
    int u = (t >= off) ? sh[t - off] : 0;
    __syncthreads();
    sh[t] += u;
    __syncthreads();
  }
  if (t < NB) part[t] = sh[t] - v;  // exclusive
}

__global__ void k_scan_fin(const int* __restrict__ cnt, const int* __restrict__ part,
                           int* __restrict__ rowptr, int N, int E) {
  __shared__ int sh[256];
  int t = threadIdx.x;
  int i = blockIdx.x * 256 + t;
  int v = (i < N) ? cnt[i] : 0;
  sh[t] = v;
  __syncthreads();
  for (int off = 1; off < 256; off <<= 1) {
    int u = (t >= off) ? sh[t - off] : 0;
    __syncthreads();
    sh[t] += u;
    __syncthreads();
  }
  if (i < N) rowptr[i] = part[blockIdx.x] + sh[t] - v;  // exclusive prefix
  if (i == 0) rowptr[N] = E;
}

// single int2 {src, eid} scattered store per edge (one cacheline touch)
__global__ void k_fill(const int* __restrict__ src, const int* __restrict__ dst,
                       const int* __restrict__ rowptr, int* __restrict__ cursor,
                       int2* __restrict__ csr2, int E) {
  int e = blockIdx.x * 256 + threadIdx.x;
  if (e < E) {
    int d = dst[e];
    int pos = rowptr[d] + atomicAdd(&cursor[d], 1);
    csr2[pos] = make_int2(src[e], e);
  }
}

// ---------------- layer-1 mean aggregation (fp8 gather, 256 cols) ----------------
// one wave per node; half-wave per source row (32 lanes x 8B), 4-deep pipeline.
__global__ void k_agg(const uint8_t* __restrict__ xq, const int* __restrict__ rowptr,
                      const int2* __restrict__ csr2, bf16* __restrict__ mean) {
  int wave = threadIdx.x >> 6, lane = threadIdx.x & 63;
  int n = blockIdx.x * 4 + wave;
  int s = rowptr[n], e = rowptr[n + 1];
  int half = lane >> 5, l32 = lane & 31;
  float a[8] = {};
  const uint8_t* base = xq + l32 * 8;
  int i = s + half;
  for (; i + 6 < e; i += 8) {
    int c0 = csr2[i].x, c1 = csr2[i + 2].x, c2 = csr2[i + 4].x, c3 = csr2[i + 6].x;
    uint2 v0 = *(const uint2*)(base + (size_t)c0 * 256);
    uint2 v1 = *(const uint2*)(base + (size_t)c1 * 256);
    uint2 v2 = *(const uint2*)(base + (size_t)c2 * 256);
    uint2 v3 = *(const uint2*)(base + (size_t)c3 * 256);
    acc_fp8x8(a, v0); acc_fp8x8(a, v1); acc_fp8x8(a, v2); acc_fp8x8(a, v3);
  }
  for (; i < e; i += 2) {
    uint2 v = *(const uint2*)(base + (size_t)csr2[i].x * 256);
    acc_fp8x8(a, v);
  }
  int deg = e - s;
  float sc = 1.0f / (float)(deg > 0 ? deg : 1);
  bf16x8 o;
#pragma unroll
  for (int j = 0; j < 8; ++j) {
    float t = a[j] + __shfl_xor(a[j], 32);
    o[j] = (bf16)(t * sc);
  }
  if (half == 0)
    *(bf16x8*)(mean + (size_t)n * 256 + l32 * 8) = o;
}

// ---------------- layer-2 aggregate+combine (fp8 hl gather, 128 cols) ----------------
// zf[n] = agg_mean(hq over neighbors) + hr[n] + b2l. Quarter-wave per row,
// 2-deep pipeline.
__global__ void k_agg2z(const uint8_t* __restrict__ hq, const bf16* __restrict__ hr,
                        const int* __restrict__ rowptr, const int2* __restrict__ csr2,
                        const float* __restrict__ b2l, bf16* __restrict__ zf) {
  int wave = threadIdx.x >> 6, lane = threadIdx.x & 63;
  int n = blockIdx.x * 4 + wave;
  int s = rowptr[n], e = rowptr[n + 1];
  int sub = lane >> 4, l16 = lane & 15;
  float a[8] = {};
  const uint8_t* base = hq + l16 * 8;
  int i = s + sub;
  for (; i + 4 < e; i += 8) {
    int c0 = csr2[i].x, c1 = csr2[i + 4].x;
    uint2 v0 = *(const uint2*)(base + (size_t)c0 * 128);
    uint2 v1 = *(const uint2*)(base + (size_t)c1 * 128);
    acc_fp8x8(a, v0); acc_fp8x8(a, v1);
  }
  for (; i < e; i += 4) {
    uint2 v = *(const uint2*)(base + (size_t)csr2[i].x * 128);
    acc_fp8x8(a, v);
  }
  int deg = e - s;
  float sc = 1.0f / (float)(deg > 0 ? deg : 1);
  bf16x8 hv = *(const bf16x8*)(hr + (size_t)n * 128 + l16 * 8);
  const float4* b4 = (const float4*)(b2l + l16 * 8);
  float4 ba = b4[0], bb = b4[1];
  float bl[8] = {ba.x, ba.y, ba.z, ba.w, bb.x, bb.y, bb.z, bb.w};
  bf16x8 o;
#pragma unroll
  for (int j = 0; j < 8; ++j) {
    float t = a[j];
    t += __shfl_xor(t, 16);
    t += __shfl_xor(t, 32);
    o[j] = (bf16)(t * sc + (float)hv[j] + bl[j]);
  }
  if (sub == 0)
    *(bf16x8*)(zf + (size_t)n * 128 + l16 * 8) = o;
}

// ---------------- SAGEConv1 GEMM: h = relu([mean|x] @ B1^T + b1l) ----------------
// grid (2, 782): col-tile fastest for twin-block A reuse.
__global__ __launch_bounds__(256) void k_conv_gemm(
    const bf16* __restrict__ A1, const bf16* __restrict__ A2,
    const bf16* __restrict__ B, const float* __restrict__ bias,
    bf16* __restrict__ out, int Nrows) {
  __shared__ bf16 As[128 * 64];
  __shared__ bf16 Bs[128 * 64];
  const int tid = threadIdx.x, wave = tid >> 6, lane = tid & 63;
  const int quad = lane >> 4, l16 = lane & 15;
  const int rowBase = blockIdx.y * 128;
  const int colBase = blockIdx.x * 128;
  const int wr = (wave >> 1) * 64;
  const int wc = (wave & 1) * 64;
  floatx4 acc[4][4] = {};

  for (int kc = 0; kc < 8; ++kc) {
    const bf16* Asrc = (kc < 4) ? A1 : A2;
    const int kb = (kc & 3) * 64;
    for (int i = 0; i < 4; ++i) {
      int u = wave * 256 + i * 64 + lane;
      int row = u >> 3, seg = u & 7;
      int sg = seg ^ (row & 7);  // swizzled global seg -> LDS seg
      int node = rowBase + row;
      if (node >= Nrows) node = Nrows - 1;
      async16(Asrc + (size_t)node * 256 + kb + sg * 8, &As[(wave * 256 + i * 64) * 8]);
    }
    for (int i = 0; i < 4; ++i) {
      int u = wave * 256 + i * 64 + lane;
      int row = u >> 3, seg = u & 7;
      int sg = seg ^ (row & 7);
      async16(B + (size_t)(colBase + row) * 512 + kc * 64 + sg * 8,
              &Bs[(wave * 256 + i * 64) * 8]);
    }
    __syncthreads();
    for (int ks = 0; ks < 2; ++ks) {
      bf16x8 af[4], bq[4];
      const int sw = (ks * 4 + quad) ^ (l16 & 7);
      for (int mt = 0; mt < 4; ++mt)
        af[mt] = *(const bf16x8*)&As[(wr + mt * 16 + l16) * 64 + sw * 8];
      for (int nt = 0; nt < 4; ++nt)
        bq[nt] = *(const bf16x8*)&Bs[(wc + nt * 16 + l16) * 64 + sw * 8];
      for (int mt = 0; mt < 4; ++mt)
        for (int nt = 0; nt < 4; ++nt)
          acc[mt][nt] = __builtin_amdgcn_mfma_f32_16x16x32_bf16(af[mt], bq[nt], acc[mt][nt], 0, 0, 0);
    }
    __syncthreads();
  }
  float bv[4];
  for (int nt = 0; nt < 4; ++nt) bv[nt] = bias[colBase + wc + nt * 16 + l16];
  for (int mt = 0; mt < 4; ++mt)
    for (int nt = 0; nt < 4; ++nt) {
      int gcol = colBase + wc + nt * 16 + l16;
      for (int r = 0; r < 4; ++r) {
        int grow = rowBase + wr + mt * 16 + quad * 4 + r;
        if (grow < Nrows) {
          float v = fmaxf(acc[mt][nt][r] + bv[nt], 0.0f);
          out[(size_t)grow * 256 + gcol] = (bf16)v;
        }
      }
    }
}

// ---------------- generic GEMM with split epilogue ----------------
// out = A[N][KDIM] @ B[256][KDIM]^T (+bias). 256 output cols split:
// EPI=1: cols<128 -> fp8 out1 [N][128], cols>=128 -> bf16 out2 [N][128] (no bias)
// EPI=2: cols<128 -> bf16 out1 (+bias), cols>=128 -> bf16 out2 (+bias)
template <int KDIM, int EPI>
__global__ __launch_bounds__(256) void k_gemm(
    const bf16* __restrict__ A, const bf16* __restrict__ B,
    const float* __restrict__ bias, void* __restrict__ out1,
    void* __restrict__ out2, int Nrows) {
  __shared__ bf16 As[128 * 64];
  __shared__ bf16 Bs[128 * 64];
  const int tid = threadIdx.x, wave = tid >> 6, lane = tid & 63;
  const int quad = lane >> 4, l16 = lane & 15;
  const int rowBase = blockIdx.y * 128;
  const int colBase = blockIdx.x * 128;
  const int wr = (wave >> 1) * 64;
  const int wc = (wave & 1) * 64;
  floatx4 acc[4][4] = {};

  for (int kc = 0; kc < KDIM / 64; ++kc) {
    for (int i = 0; i < 4; ++i) {
      int u = wave * 256 + i * 64 + lane;
      int row = u >> 3, seg = u & 7;
      int sg = seg ^ (row & 7);
      int node = rowBase + row;
      if (node >= Nrows) node = Nrows - 1;
      async16(A + (size_t)node * KDIM + kc * 64 + sg * 8, &As[(wave * 256 + i * 64) * 8]);
    }
    for (int i = 0; i < 4; ++i) {
      int u = wave * 256 + i * 64 + lane;
      int row = u >> 3, seg = u & 7;
      int sg = seg ^ (row & 7);
      async16(B + (size_t)(colBase + row) * KDIM + kc * 64 + sg * 8,
              &Bs[(wave * 256 + i * 64) * 8]);
    }
    __syncthreads();
    for (int ks = 0; ks < 2; ++ks) {
      bf16x8 af[4], bq[4];
      const int sw = (ks * 4 + quad) ^ (l16 & 7);
      for (int mt = 0; mt < 4; ++mt)
        af[mt] = *(const bf16x8*)&As[(wr + mt * 16 + l16) * 64 + sw * 8];
      for (int nt = 0; nt < 4; ++nt)
        bq[nt] = *(const bf16x8*)&Bs[(wc + nt * 16 + l16) * 64 + sw * 8];
      for (int mt = 0; mt < 4; ++mt)
        for (int nt = 0; nt < 4; ++nt)
          acc[mt][nt] = __builtin_amdgcn_mfma_f32_16x16x32_bf16(af[mt], bq[nt], acc[mt][nt], 0, 0, 0);
    }
    __syncthreads();
  }
  float bv[4];
  for (int nt = 0; nt < 4; ++nt)
    bv[nt] = (EPI == 2) ? bias[colBase + wc + nt * 16 + l16] : 0.0f;
  const bool lowHalf = (colBase == 0);  // 256-col output, tile 0 = cols<128
  for (int mt = 0; mt < 4; ++mt)
    for (int nt = 0; nt < 4; ++nt) {
      int gcol = colBase + wc + nt * 16 + l16;
      for (int r = 0; r < 4; ++r) {
        int grow = rowBase + wr + mt * 16 + quad * 4 + r;
        if (grow < Nrows) {
          float v = acc[mt][nt][r] + bv[nt];
          if (lowHalf) {
            if (EPI == 1) {
              uint32_t pk = (uint32_t)__builtin_amdgcn_cvt_pk_fp8_f32(v, v, 0, false);
              ((uint8_t*)out1)[(size_t)grow * 128 + gcol] = (uint8_t)pk;
            } else {
              ((bf16*)out1)[(size_t)grow * 128 + gcol] = (bf16)v;
            }
          } else {
            ((bf16*)out2)[(size_t)grow * 128 + gcol - 128] = (bf16)v;
          }
        }
      }
    }
}

// ---------------- edge decoder, CSR-ordered ----------------
// out[eid] = sum_o relu(P[src][o]+Q[d][o]) * wd2[o] + bd2.
// one wave per dst node; quarter-wave (16 lanes x 8 cols) per edge.
__global__ __launch_bounds__(256) void k_edge(
    const bf16* __restrict__ P, const bf16* __restrict__ Q,
    const int* __restrict__ rowptr, const int2* __restrict__ csr2,
    const float* __restrict__ wd2, const float* __restrict__ bd2,
    float* __restrict__ out) {
  int wave = threadIdx.x >> 6, lane = threadIdx.x & 63;
  int n = blockIdx.x * 4 + wave;
  int s = rowptr[n], e = rowptr[n + 1];
  int sub = lane >> 4, l16 = lane & 15;
  bf16x8 qv = *(const bf16x8*)(Q + (size_t)n * 128 + l16 * 8);
  float qf[8];
#pragma unroll
  for (int j = 0; j < 8; ++j) qf[j] = (float)qv[j];
  const float4* w4 = (const float4*)(wd2 + l16 * 8);
  float4 wa = w4[0], wb = w4[1];
  float w[8] = {wa.x, wa.y, wa.z, wa.w, wb.x, wb.y, wb.z, wb.w};
  const float bout = bd2[0];
  int i = s + sub;
  for (; i + 4 < e; i += 8) {
    int2 ce0 = csr2[i], ce1 = csr2[i + 4];
    bf16x8 p0 = *(const bf16x8*)(P + (size_t)ce0.x * 128 + l16 * 8);
    bf16x8 p1 = *(const bf16x8*)(P + (size_t)ce1.x * 128 + l16 * 8);
    float a0 = 0.f, a1 = 0.f;
#pragma unroll
    for (int j = 0; j < 8; ++j) {
      a0 += fmaxf((float)p0[j] + qf[j], 0.f) * w[j];
      a1 += fmaxf((float)p1[j] + qf[j], 0.f) * w[j];
    }
    a0 += __shfl_xor(a0, 1); a1 += __shfl_xor(a1, 1);
    a0 += __shfl_xor(a0, 2); a1 += __shfl_xor(a1, 2);
    a0 += __shfl_xor(a0, 4); a1 += __shfl_xor(a1, 4);
    a0 += __shfl_xor(a0, 8); a1 += __shfl_xor(a1, 8);
    if (l16 == 0) { out[ce0.y] = a0 + bout; out[ce1.y] = a1 + bout; }
  }
  for (; i < e; i += 4) {
    int2 ce = csr2[i];
    bf16x8 p = *(const bf16x8*)(P + (size_t)ce.x * 128 + l16 * 8);
    float a = 0.f;
#pragma unroll
    for (int j = 0; j < 8; ++j)
      a += fmaxf((float)p[j] + qf[j], 0.f) * w[j];
    a += __shfl_xor(a, 1);
    a += __shfl_xor(a, 2);
    a += __shfl_xor(a, 4);
    a += __shfl_xor(a, 8);
    if (l16 == 0) out[ce.y] = a + bout;
  }
}

// ---------------- host ----------------
extern "C" void kernel_launch(void* const* d_in, const int* in_sizes, int n_in,
                              void* d_out, int out_size, void* d_ws, size_t ws_size,
                              hipStream_t stream) {
  const float* x   = (const float*)d_in[0];
  const int*   ei  = (const int*)d_in[1];
  const float* W1l = (const float*)d_in[2];
  const float* b1l = (const float*)d_in[3];
  const float* W1r = (const float*)d_in[4];
  const float* W2l = (const float*)d_in[5];
  const float* b2l = (const float*)d_in[6];
  const float* W2r = (const float*)d_in[7];
  const float* Wd1 = (const float*)d_in[8];
  const float* bd1 = (const float*)d_in[9];
  const float* Wd2 = (const float*)d_in[10];
  const float* bd2 = (const float*)d_in[11];
  float* out = (float*)d_out;

  const int N = NN, E = NE;
  const int* srcv = ei;
  const int* dstv = ei + E;

  char* w = (char*)d_ws;
  size_t off = 0;
  auto take = [&](size_t bytes) {
    size_t o = off;
    off = (off + bytes + 255) & ~(size_t)255;
    return o;
  };
  int*      cnt    = (int*)(w + take((size_t)N * 4));
  int*      cursor = (int*)(w + take((size_t)N * 4));
  int*      rowptr = (int*)(w + take((size_t)(N + 1) * 4));
  int*      part   = (int*)(w + take((size_t)NB_SCAN * 4));
  int2*     csr2   = (int2*)(w + take((size_t)E * 8));
  bf16*     xb     = (bf16*)(w + take((size_t)N * 256 * 2));
  uint8_t*  xq     = (uint8_t*)(w + take((size_t)N * 256));
  bf16*     mean   = (bf16*)(w + take((size_t)N * 256 * 2));  // reused: hq+hr
  bf16*     h      = (bf16*)(w + take((size_t)N * 256 * 2));  // reused: P+Q
  bf16*     zf     = (bf16*)(w + take((size_t)N * 128 * 2));
  bf16*     B1     = (bf16*)(w + take((size_t)131072 * 2));
  bf16*     B2     = (bf16*)(w + take((size_t)65536 * 2));
  bf16*     Bd     = (bf16*)(w + take((size_t)32768 * 2));
  float*    biasPQ = (float*)(w + take((size_t)256 * 4));
  // aliases (producer/consumer ordering makes these safe):
  uint8_t* hq = (uint8_t*)mean;                 // [N][128] fp8, after conv1
  bf16*    hr = (bf16*)(hq + (size_t)N * 128);  // [N][128] bf16
  bf16*    P  = h;                              // [N][128] bf16, after gemm256
  bf16*    Q  = h + (size_t)N * 128;            // [N][128] bf16
  (void)ws_size; (void)n_in; (void)in_sizes; (void)out_size;

  hipMemsetAsync(cnt, 0, (size_t)((char*)rowptr - (char*)cnt), stream);

  k_cvtx_hist<<<NB_CVTX + NB_HIST, 256, 0, stream>>>(x, xb, (uint32_t*)xq, dstv, cnt);
  k_cvtw_scanpart<<<NB_CVTW + NB_SCAN, 256, 0, stream>>>(
      W1l, W1r, W2l, W2r, Wd1, bd1, B1, B2, Bd, biasPQ, cnt, part, N);
  k_scan_mid<<<1, 512, 0, stream>>>(part, NB_SCAN);
  k_scan_fin<<<NB_SCAN, 256, 0, stream>>>(cnt, part, rowptr, N, E);
  k_fill<<<E / 256, 256, 0, stream>>>(srcv, dstv, rowptr, cursor, csr2, E);

  // conv1: h = relu([mean|x] @ [W1l|W1r]^T + b1l)
  k_agg<<<N / 4, 256, 0, stream>>>(xq, rowptr, csr2, mean);
  k_conv_gemm<<<dim3(2, 782), 256, 0, stream>>>(mean, xb, B1, b1l, h, N);
  // conv2 (transform-then-aggregate): [hq|hr] = h @ [W2l;W2r]^T (hq fp8),
  // then zf = agg_mean(hq) + hr + b2l
  k_gemm<256, 1><<<dim3(2, 782), 256, 0, stream>>>(h, B2, nullptr, hq, hr, N);
  k_agg2z<<<N / 4, 256, 0, stream>>>(hq, hr, rowptr, csr2, b2l, zf);
  // decoder node-level: [P|Q] = zf @ Bd^T + [bd1|0]
  k_gemm<128, 2><<<dim3(2, 782), 256, 0, stream>>>(zf, Bd, biasPQ, P, Q, N);
  // decoder edge-level, CSR-ordered (Q dense per node, P gathered)
  k_edge<<<N / 4, 256, 0, stream>>>(P, Q, rowptr, csr2, Wd2, bd2, out);
}

// Round 7
// 602.786 us; speedup vs baseline: 1.8667x; 1.0954x over previous
//
#include <hip/hip_runtime.h>
#include <stdint.h>

// GNNAutoEncoder: 2x SAGEConv(mean) + edge MLP decoder.
// N=100000 nodes, E=1600000 edges, D=256, HIDDEN=256, OUT=128.
static constexpr int NN = 100000;
static constexpr int NE = 1600000;
static constexpr int NB_SCAN = (NN + 255) / 256;  // 391
static constexpr int NB_CVTX = NN * 256 / 4 / 256;  // 25000
static constexpr int NB_HIST = NE / 256;            // 6250
static constexpr int NB_CVTW = 897;

typedef __bf16 bf16;
typedef __bf16 bf16x4 __attribute__((ext_vector_type(4)));
typedef __bf16 bf16x8 __attribute__((ext_vector_type(8)));
typedef float floatx4 __attribute__((ext_vector_type(4)));

// async global->LDS, 16B per lane. LDS dest is wave-uniform base + lane*16.
__device__ __forceinline__ void async16(const void* g, void* l) {
  __builtin_amdgcn_global_load_lds(
      (const __attribute__((address_space(1))) void*)g,
      (__attribute__((address_space(3))) void*)l, 16, 0, 0);
}

// pack 4 floats -> 4 OCP e4m3 bytes
__device__ __forceinline__ uint32_t pk4_fp8(float a, float b, float c, float d) {
  uint32_t v = 0;
  v = (uint32_t)__builtin_amdgcn_cvt_pk_fp8_f32(a, b, (int)v, false);
  v = (uint32_t)__builtin_amdgcn_cvt_pk_fp8_f32(c, d, (int)v, true);
  return v;
}

// accumulate 8 fp8 (uint2) into float[8]
__device__ __forceinline__ void acc_fp8x8(float* a, uint2 v) {
  a[0] += __builtin_amdgcn_cvt_f32_fp8(v.x, 0);
  a[1] += __builtin_amdgcn_cvt_f32_fp8(v.x, 1);
  a[2] += __builtin_amdgcn_cvt_f32_fp8(v.x, 2);
  a[3] += __builtin_amdgcn_cvt_f32_fp8(v.x, 3);
  a[4] += __builtin_amdgcn_cvt_f32_fp8(v.y, 0);
  a[5] += __builtin_amdgcn_cvt_f32_fp8(v.y, 1);
  a[6] += __builtin_amdgcn_cvt_f32_fp8(v.y, 2);
  a[7] += __builtin_amdgcn_cvt_f32_fp8(v.y, 3);
}

// ---------------- fused: x->bf16+fp8 convert | dst histogram + rank ----------------
// The histogram atomic's return value IS the edge's within-row rank; store it
// so the CSR fill needs no atomic at all.
__global__ void k_cvtx_hist(const float* __restrict__ x, bf16* __restrict__ xb,
                            uint32_t* __restrict__ xq,
                            const int* __restrict__ dst, int* __restrict__ cnt,
                            uint16_t* __restrict__ rank) {
  int b = blockIdx.x;
  if (b < NB_CVTX) {
    int t = b * 256 + threadIdx.x;  // 4 elems / thread
    const float4 v = ((const float4*)x)[t];
    bf16x4 o;
    o.x = (bf16)v.x; o.y = (bf16)v.y; o.z = (bf16)v.z; o.w = (bf16)v.w;
    ((bf16x4*)xb)[t] = o;
    xq[t] = pk4_fp8(v.x, v.y, v.z, v.w);
  } else {
    int e = (b - NB_CVTX) * 256 + threadIdx.x;
    int old = atomicAdd(&cnt[dst[e]], 1);
    rank[e] = (uint16_t)old;
  }
}

// ---------------- fused: weight packs | scan partials ----------------
// B1 = [W1l | W1r] as [256][512]; B2 = [W2l ; W2r] stacked as [256][256];
// Bd = [Wd1[:, :128] ; Wd1[:, 128:]] as [256][128]; biasPQ = [bd1 | 0] (256 f32).
__global__ void k_cvtw_scanpart(
    const float* __restrict__ W1l, const float* __restrict__ W1r,
    const float* __restrict__ W2l, const float* __restrict__ W2r,
    const float* __restrict__ Wd1, const float* __restrict__ bd1,
    bf16* __restrict__ B1, bf16* __restrict__ B2,
    bf16* __restrict__ Bd, float* __restrict__ biasPQ,
    const int* __restrict__ cnt, int* __restrict__ part, int N) {
  int b = blockIdx.x;
  if (b < NB_CVTW) {
    int g = b * 256 + threadIdx.x;  // 229632 total
    if (g < 131072) {
      int o = g >> 9, k = g & 511;
      float v = (k < 256) ? W1l[o * 256 + k] : W1r[o * 256 + k - 256];
      B1[g] = (bf16)v;
    } else if (g < 131072 + 65536) {
      int t = g - 131072;
      int o = t >> 8, k = t & 255;
      float v = (o < 128) ? W2l[o * 256 + k] : W2r[(o - 128) * 256 + k];
      B2[t] = (bf16)v;
    } else if (g < 131072 + 65536 + 32768) {
      int t = g - 196608;
      int o = t >> 7, k = t & 127;
      float v = (o < 128) ? Wd1[o * 256 + k] : Wd1[(o - 128) * 256 + 128 + k];
      Bd[t] = (bf16)v;
    } else if (g < 131072 + 65536 + 32768 + 256) {
      int t = g - 229376;
      biasPQ[t] = (t < 128) ? bd1[t] : 0.0f;
    }
  } else {
    __shared__ int sh[256];
    int bb = b - NB_CVTW;
    int t = threadIdx.x;
    int i = bb * 256 + t;
    sh[t] = (i < N) ? cnt[i] : 0;
    __syncthreads();
    for (int off = 128; off > 0; off >>= 1) {
      if (t < off) sh[t] += sh[t + off];
      __syncthreads();
    }
    if (t == 0) part[bb] = sh[0];
  }
}

__global__ __launch_bounds__(512) void k_scan_mid(int* __restrict__ part, int NB) {
  __shared__ int sh[512];
  int t = threadIdx.x;
  int v = (t < NB) ? part[t] : 0;
  sh[t] = v;
  __syncthreads();
  for (int off = 1; off < 512; off <<= 1) {
    int u = (t >= off) ? sh[t - off] : 0;
    __syncthreads();
    sh[t] += u;
    __syncthreads();
  }
  if (t < NB) part[t] = sh[t] - v;  // exclusive
}

__global__ void k_scan_fin(const int* __restrict__ cnt, const int* __restrict__ part,
                           int* __restrict__ rowptr, int N, int E) {
  __shared__ int sh[256];
  int t = threadIdx.x;
  int i = blockIdx.x * 256 + t;
  int v = (i < N) ? cnt[i] : 0;
  sh[t] = v;
  __syncthreads();
  for (int off = 1; off < 256; off <<= 1) {
    int u = (t >= off) ? sh[t - off] : 0;
    __syncthreads();
    sh[t] += u;
    __syncthreads();
  }
  if (i < N) rowptr[i] = part[blockIdx.x] + sh[t] - v;  // exclusive prefix
  if (i == 0) rowptr[N] = E;
}

// atomic-free CSR fill: pos = rowptr[dst] + rank (rank captured in hist).
// single int2 {src, eid} scattered store per edge.
__global__ void k_fill(const int* __restrict__ src, const int* __restrict__ dst,
                       const int* __restrict__ rowptr,
                       const uint16_t* __restrict__ rank,
                       int2* __restrict__ csr2, int E) {
  int e = blockIdx.x * 256 + threadIdx.x;
  if (e < E) {
    int d = dst[e];
    int pos = rowptr[d] + (int)rank[e];
    csr2[pos] = make_int2(src[e], e);
  }
}

// ---------------- layer-1 mean aggregation (fp8 gather, 256 cols) ----------------
// one wave per node; half-wave per source row (32 lanes x 8B), 4-deep pipeline.
__global__ void k_agg(const uint8_t* __restrict__ xq, const int* __restrict__ rowptr,
                      const int2* __restrict__ csr2, bf16* __restrict__ mean) {
  int wave = threadIdx.x >> 6, lane = threadIdx.x & 63;
  int n = blockIdx.x * 4 + wave;
  int s = rowptr[n], e = rowptr[n + 1];
  int half = lane >> 5, l32 = lane & 31;
  float a[8] = {};
  const uint8_t* base = xq + l32 * 8;
  int i = s + half;
  for (; i + 6 < e; i += 8) {
    int c0 = csr2[i].x, c1 = csr2[i + 2].x, c2 = csr2[i + 4].x, c3 = csr2[i + 6].x;
    uint2 v0 = *(const uint2*)(base + (size_t)c0 * 256);
    uint2 v1 = *(const uint2*)(base + (size_t)c1 * 256);
    uint2 v2 = *(const uint2*)(base + (size_t)c2 * 256);
    uint2 v3 = *(const uint2*)(base + (size_t)c3 * 256);
    acc_fp8x8(a, v0); acc_fp8x8(a, v1); acc_fp8x8(a, v2); acc_fp8x8(a, v3);
  }
  for (; i < e; i += 2) {
    uint2 v = *(const uint2*)(base + (size_t)csr2[i].x * 256);
    acc_fp8x8(a, v);
  }
  int deg = e - s;
  float sc = 1.0f / (float)(deg > 0 ? deg : 1);
  bf16x8 o;
#pragma unroll
  for (int j = 0; j < 8; ++j) {
    float t = a[j] + __shfl_xor(a[j], 32);
    o[j] = (bf16)(t * sc);
  }
  if (half == 0)
    *(bf16x8*)(mean + (size_t)n * 256 + l32 * 8) = o;
}

// ---------------- layer-2 aggregate+combine (fp8 hl gather, 128 cols) ----------------
// zf[n] = agg_mean(hq over neighbors) + hr[n] + b2l. Quarter-wave per row,
// 2-deep pipeline.
__global__ void k_agg2z(const uint8_t* __restrict__ hq, const bf16* __restrict__ hr,
                        const int* __restrict__ rowptr, const int2* __restrict__ csr2,
                        const float* __restrict__ b2l, bf16* __restrict__ zf) {
  int wave = threadIdx.x >> 6, lane = threadIdx.x & 63;
  int n = blockIdx.x * 4 + wave;
  int s = rowptr[n], e = rowptr[n + 1];
  int sub = lane >> 4, l16 = lane & 15;
  float a[8] = {};
  const uint8_t* base = hq + l16 * 8;
  int i = s + sub;
  for (; i + 4 < e; i += 8) {
    int c0 = csr2[i].x, c1 = csr2[i + 4].x;
    uint2 v0 = *(const uint2*)(base + (size_t)c0 * 128);
    uint2 v1 = *(const uint2*)(base + (size_t)c1 * 128);
    acc_fp8x8(a, v0); acc_fp8x8(a, v1);
  }
  for (; i < e; i += 4) {
    uint2 v = *(const uint2*)(base + (size_t)csr2[i].x * 128);
    acc_fp8x8(a, v);
  }
  int deg = e - s;
  float sc = 1.0f / (float)(deg > 0 ? deg : 1);
  bf16x8 hv = *(const bf16x8*)(hr + (size_t)n * 128 + l16 * 8);
  const float4* b4 = (const float4*)(b2l + l16 * 8);
  float4 ba = b4[0], bb = b4[1];
  float bl[8] = {ba.x, ba.y, ba.z, ba.w, bb.x, bb.y, bb.z, bb.w};
  bf16x8 o;
#pragma unroll
  for (int j = 0; j < 8; ++j) {
    float t = a[j];
    t += __shfl_xor(t, 16);
    t += __shfl_xor(t, 32);
    o[j] = (bf16)(t * sc + (float)hv[j] + bl[j]);
  }
  if (sub == 0)
    *(bf16x8*)(zf + (size_t)n * 128 + l16 * 8) = o;
}

// ---------------- SAGEConv1 GEMM: h = relu([mean|x] @ B1^T + b1l) ----------------
// grid (2, 782): col-tile fastest for twin-block A reuse.
__global__ __launch_bounds__(256) void k_conv_gemm(
    const bf16* __restrict__ A1, const bf16* __restrict__ A2,
    const bf16* __restrict__ B, const float* __restrict__ bias,
    bf16* __restrict__ out, int Nrows) {
  __shared__ bf16 As[128 * 64];
  __shared__ bf16 Bs[128 * 64];
  const int tid = threadIdx.x, wave = tid >> 6, lane = tid & 63;
  const int quad = lane >> 4, l16 = lane & 15;
  const int rowBase = blockIdx.y * 128;
  const int colBase = blockIdx.x * 128;
  const int wr = (wave >> 1) * 64;
  const int wc = (wave & 1) * 64;
  floatx4 acc[4][4] = {};

  for (int kc = 0; kc < 8; ++kc) {
    const bf16* Asrc = (kc < 4) ? A1 : A2;
    const int kb = (kc & 3) * 64;
    for (int i = 0; i < 4; ++i) {
      int u = wave * 256 + i * 64 + lane;
      int row = u >> 3, seg = u & 7;
      int sg = seg ^ (row & 7);  // swizzled global seg -> LDS seg
      int node = rowBase + row;
      if (node >= Nrows) node = Nrows - 1;
      async16(Asrc + (size_t)node * 256 + kb + sg * 8, &As[(wave * 256 + i * 64) * 8]);
    }
    for (int i = 0; i < 4; ++i) {
      int u = wave * 256 + i * 64 + lane;
      int row = u >> 3, seg = u & 7;
      int sg = seg ^ (row & 7);
      async16(B + (size_t)(colBase + row) * 512 + kc * 64 + sg * 8,
              &Bs[(wave * 256 + i * 64) * 8]);
    }
    __syncthreads();
    for (int ks = 0; ks < 2; ++ks) {
      bf16x8 af[4], bq[4];
      const int sw = (ks * 4 + quad) ^ (l16 & 7);
      for (int mt = 0; mt < 4; ++mt)
        af[mt] = *(const bf16x8*)&As[(wr + mt * 16 + l16) * 64 + sw * 8];
      for (int nt = 0; nt < 4; ++nt)
        bq[nt] = *(const bf16x8*)&Bs[(wc + nt * 16 + l16) * 64 + sw * 8];
      for (int mt = 0; mt < 4; ++mt)
        for (int nt = 0; nt < 4; ++nt)
          acc[mt][nt] = __builtin_amdgcn_mfma_f32_16x16x32_bf16(af[mt], bq[nt], acc[mt][nt], 0, 0, 0);
    }
    __syncthreads();
  }
  float bv[4];
  for (int nt = 0; nt < 4; ++nt) bv[nt] = bias[colBase + wc + nt * 16 + l16];
  for (int mt = 0; mt < 4; ++mt)
    for (int nt = 0; nt < 4; ++nt) {
      int gcol = colBase + wc + nt * 16 + l16;
      for (int r = 0; r < 4; ++r) {
        int grow = rowBase + wr + mt * 16 + quad * 4 + r;
        if (grow < Nrows) {
          float v = fmaxf(acc[mt][nt][r] + bv[nt], 0.0f);
          out[(size_t)grow * 256 + gcol] = (bf16)v;
        }
      }
    }
}

// ---------------- generic GEMM with split epilogue ----------------
// out = A[N][KDIM] @ B[256][KDIM]^T (+bias). 256 output cols split:
// EPI=1: cols<128 -> fp8 out1 [N][128], cols>=128 -> bf16 out2 [N][128] (no bias)
// EPI=2: cols<128 -> bf16 out1 (+bias), cols>=128 -> bf16 out2 (+bias)
template <int KDIM, int EPI>
__global__ __launch_bounds__(256) void k_gemm(
    const bf16* __restrict__ A, const bf16* __restrict__ B,
    const float* __restrict__ bias, void* __restrict__ out1,
    void* __restrict__ out2, int Nrows) {
  __shared__ bf16 As[128 * 64];
  __shared__ bf16 Bs[128 * 64];
  const int tid = threadIdx.x, wave = tid >> 6, lane = tid & 63;
  const int quad = lane >> 4, l16 = lane & 15;
  const int rowBase = blockIdx.y * 128;
  const int colBase = blockIdx.x * 128;
  const int wr = (wave >> 1) * 64;
  const int wc = (wave & 1) * 64;
  floatx4 acc[4][4] = {};

  for (int kc = 0; kc < KDIM / 64; ++kc) {
    for (int i = 0; i < 4; ++i) {
      int u = wave * 256 + i * 64 + lane;
      int row = u >> 3, seg = u & 7;
      int sg = seg ^ (row & 7);
      int node = rowBase + row;
      if (node >= Nrows) node = Nrows - 1;
      async16(A + (size_t)node * KDIM + kc * 64 + sg * 8, &As[(wave * 256 + i * 64) * 8]);
    }
    for (int i = 0; i < 4; ++i) {
      int u = wave * 256 + i * 64 + lane;
      int row = u >> 3, seg = u & 7;
      int sg = seg ^ (row & 7);
      async16(B + (size_t)(colBase + row) * KDIM + kc * 64 + sg * 8,
              &Bs[(wave * 256 + i * 64) * 8]);
    }
    __syncthreads();
    for (int ks = 0; ks < 2; ++ks) {
      bf16x8 af[4], bq[4];
      const int sw = (ks * 4 + quad) ^ (l16 & 7);
      for (int mt = 0; mt < 4; ++mt)
        af[mt] = *(const bf16x8*)&As[(wr + mt * 16 + l16) * 64 + sw * 8];
      for (int nt = 0; nt < 4; ++nt)
        bq[nt] = *(const bf16x8*)&Bs[(wc + nt * 16 + l16) * 64 + sw * 8];
      for (int mt = 0; mt < 4; ++mt)
        for (int nt = 0; nt < 4; ++nt)
          acc[mt][nt] = __builtin_amdgcn_mfma_f32_16x16x32_bf16(af[mt], bq[nt], acc[mt][nt], 0, 0, 0);
    }
    __syncthreads();
  }
  float bv[4];
  for (int nt = 0; nt < 4; ++nt)
    bv[nt] = (EPI == 2) ? bias[colBase + wc + nt * 16 + l16] : 0.0f;
  const bool lowHalf = (colBase == 0);  // 256-col output, tile 0 = cols<128
  for (int mt = 0; mt < 4; ++mt)
    for (int nt = 0; nt < 4; ++nt) {
      int gcol = colBase + wc + nt * 16 + l16;
      for (int r = 0; r < 4; ++r) {
        int grow = rowBase + wr + mt * 16 + quad * 4 + r;
        if (grow < Nrows) {
          float v = acc[mt][nt][r] + bv[nt];
          if (lowHalf) {
            if (EPI == 1) {
              uint32_t pk = (uint32_t)__builtin_amdgcn_cvt_pk_fp8_f32(v, v, 0, false);
              ((uint8_t*)out1)[(size_t)grow * 128 + gcol] = (uint8_t)pk;
            } else {
              ((bf16*)out1)[(size_t)grow * 128 + gcol] = (bf16)v;
            }
          } else {
            ((bf16*)out2)[(size_t)grow * 128 + gcol - 128] = (bf16)v;
          }
        }
      }
    }
}

// ---------------- edge decoder, CSR-ordered ----------------
// out[eid] = sum_o relu(P[src][o]+Q[d][o]) * wd2[o] + bd2.
// one wave per dst node; quarter-wave (16 lanes x 8 cols) per edge.
__global__ __launch_bounds__(256) void k_edge(
    const bf16* __restrict__ P, const bf16* __restrict__ Q,
    const int* __restrict__ rowptr, const int2* __restrict__ csr2,
    const float* __restrict__ wd2, const float* __restrict__ bd2,
    float* __restrict__ out) {
  int wave = threadIdx.x >> 6, lane = threadIdx.x & 63;
  int n = blockIdx.x * 4 + wave;
  int s = rowptr[n], e = rowptr[n + 1];
  int sub = lane >> 4, l16 = lane & 15;
  bf16x8 qv = *(const bf16x8*)(Q + (size_t)n * 128 + l16 * 8);
  float qf[8];
#pragma unroll
  for (int j = 0; j < 8; ++j) qf[j] = (float)qv[j];
  const float4* w4 = (const float4*)(wd2 + l16 * 8);
  float4 wa = w4[0], wb = w4[1];
  float w[8] = {wa.x, wa.y, wa.z, wa.w, wb.x, wb.y, wb.z, wb.w};
  const float bout = bd2[0];
  int i = s + sub;
  for (; i + 4 < e; i += 8) {
    int2 ce0 = csr2[i], ce1 = csr2[i + 4];
    bf16x8 p0 = *(const bf16x8*)(P + (size_t)ce0.x * 128 + l16 * 8);
    bf16x8 p1 = *(const bf16x8*)(P + (size_t)ce1.x * 128 + l16 * 8);
    float a0 = 0.f, a1 = 0.f;
#pragma unroll
    for (int j = 0; j < 8; ++j) {
      a0 += fmaxf((float)p0[j] + qf[j], 0.f) * w[j];
      a1 += fmaxf((float)p1[j] + qf[j], 0.f) * w[j];
    }
    a0 += __shfl_xor(a0, 1); a1 += __shfl_xor(a1, 1);
    a0 += __shfl_xor(a0, 2); a1 += __shfl_xor(a1, 2);
    a0 += __shfl_xor(a0, 4); a1 += __shfl_xor(a1, 4);
    a0 += __shfl_xor(a0, 8); a1 += __shfl_xor(a1, 8);
    if (l16 == 0) { out[ce0.y] = a0 + bout; out[ce1.y] = a1 + bout; }
  }
  for (; i < e; i += 4) {
    int2 ce = csr2[i];
    bf16x8 p = *(const bf16x8*)(P + (size_t)ce.x * 128 + l16 * 8);
    float a = 0.f;
#pragma unroll
    for (int j = 0; j < 8; ++j)
      a += fmaxf((float)p[j] + qf[j], 0.f) * w[j];
    a += __shfl_xor(a, 1);
    a += __shfl_xor(a, 2);
    a += __shfl_xor(a, 4);
    a += __shfl_xor(a, 8);
    if (l16 == 0) out[ce.y] = a + bout;
  }
}

// ---------------- host ----------------
extern "C" void kernel_launch(void* const* d_in, const int* in_sizes, int n_in,
                              void* d_out, int out_size, void* d_ws, size_t ws_size,
                              hipStream_t stream) {
  const float* x   = (const float*)d_in[0];
  const int*   ei  = (const int*)d_in[1];
  const float* W1l = (const float*)d_in[2];
  const float* b1l = (const float*)d_in[3];
  const float* W1r = (const float*)d_in[4];
  const float* W2l = (const float*)d_in[5];
  const float* b2l = (const float*)d_in[6];
  const float* W2r = (const float*)d_in[7];
  const float* Wd1 = (const float*)d_in[8];
  const float* bd1 = (const float*)d_in[9];
  const float* Wd2 = (const float*)d_in[10];
  const float* bd2 = (const float*)d_in[11];
  float* out = (float*)d_out;

  const int N = NN, E = NE;
  const int* srcv = ei;
  const int* dstv = ei + E;

  char* w = (char*)d_ws;
  size_t off = 0;
  auto take = [&](size_t bytes) {
    size_t o = off;
    off = (off + bytes + 255) & ~(size_t)255;
    return o;
  };
  int*      cnt    = (int*)(w + take((size_t)N * 4));
  int*      rowptr = (int*)(w + take((size_t)(N + 1) * 4));
  int*      part   = (int*)(w + take((size_t)NB_SCAN * 4));
  uint16_t* rank   = (uint16_t*)(w + take((size_t)E * 2));
  int2*     csr2   = (int2*)(w + take((size_t)E * 8));
  bf16*     xb     = (bf16*)(w + take((size_t)N * 256 * 2));
  uint8_t*  xq     = (uint8_t*)(w + take((size_t)N * 256));
  bf16*     mean   = (bf16*)(w + take((size_t)N * 256 * 2));  // reused: hq+hr
  bf16*     h      = (bf16*)(w + take((size_t)N * 256 * 2));  // reused: P+Q
  bf16*     zf     = (bf16*)(w + take((size_t)N * 128 * 2));
  bf16*     B1     = (bf16*)(w + take((size_t)131072 * 2));
  bf16*     B2     = (bf16*)(w + take((size_t)65536 * 2));
  bf16*     Bd     = (bf16*)(w + take((size_t)32768 * 2));
  float*    biasPQ = (float*)(w + take((size_t)256 * 4));
  // aliases (producer/consumer ordering makes these safe):
  uint8_t* hq = (uint8_t*)mean;                 // [N][128] fp8, after conv1
  bf16*    hr = (bf16*)(hq + (size_t)N * 128);  // [N][128] bf16
  bf16*    P  = h;                              // [N][128] bf16, after gemm256
  bf16*    Q  = h + (size_t)N * 128;            // [N][128] bf16
  (void)ws_size; (void)n_in; (void)in_sizes; (void)out_size;

  hipMemsetAsync(cnt, 0, (size_t)N * 4, stream);

  k_cvtx_hist<<<NB_CVTX + NB_HIST, 256, 0, stream>>>(x, xb, (uint32_t*)xq, dstv, cnt, rank);
  k_cvtw_scanpart<<<NB_CVTW + NB_SCAN, 256, 0, stream>>>(
      W1l, W1r, W2l, W2r, Wd1, bd1, B1, B2, Bd, biasPQ, cnt, part, N);
  k_scan_mid<<<1, 512, 0, stream>>>(part, NB_SCAN);
  k_scan_fin<<<NB_SCAN, 256, 0, stream>>>(cnt, part, rowptr, N, E);
  k_fill<<<E / 256, 256, 0, stream>>>(srcv, dstv, rowptr, rank, csr2, E);

  // conv1: h = relu([mean|x] @ [W1l|W1r]^T + b1l)
  k_agg<<<N / 4, 256, 0, stream>>>(xq, rowptr, csr2, mean);
  k_conv_gemm<<<dim3(2, 782), 256, 0, stream>>>(mean, xb, B1, b1l, h, N);
  // conv2 (transform-then-aggregate): [hq|hr] = h @ [W2l;W2r]^T (hq fp8),
  // then zf = agg_mean(hq) + hr + b2l
  k_gemm<256, 1><<<dim3(2, 782), 256, 0, stream>>>(h, B2, nullptr, hq, hr, N);
  k_agg2z<<<N / 4, 256, 0, stream>>>(hq, hr, rowptr, csr2, b2l, zf);
  // decoder node-level: [P|Q] = zf @ Bd^T + [bd1|0]
  k_gemm<128, 2><<<dim3(2, 782), 256, 0, stream>>>(zf, Bd, biasPQ, P, Q, N);
  // decoder edge-level, CSR-ordered (Q dense per node, P gathered)
  k_edge<<<N / 4, 256, 0, stream>>>(P, Q, rowptr, csr2, Wd2, bd2, out);
}

// Round 8
// 576.049 us; speedup vs baseline: 1.9533x; 1.0464x over previous
//
#include <hip/hip_runtime.h>
#include <stdint.h>

// GNNAutoEncoder: 2x SAGEConv(mean) + edge MLP decoder.
// N=100000 nodes, E=1600000 edges, D=256, HIDDEN=256, OUT=128.
static constexpr int NN = 100000;
static constexpr int NE = 1600000;
static constexpr int NB_SCAN = (NN + 255) / 256;  // 391
static constexpr int NB_CVTX = NN * 256 / 4 / 256;  // 25000
static constexpr int NB_HIST = NE / 256;            // 6250
static constexpr int NB_CVTW = 897;

typedef __bf16 bf16;
typedef __bf16 bf16x4 __attribute__((ext_vector_type(4)));
typedef __bf16 bf16x8 __attribute__((ext_vector_type(8)));
typedef float floatx4 __attribute__((ext_vector_type(4)));

// async global->LDS, 16B per lane. LDS dest is wave-uniform base + lane*16.
__device__ __forceinline__ void async16(const void* g, void* l) {
  __builtin_amdgcn_global_load_lds(
      (const __attribute__((address_space(1))) void*)g,
      (__attribute__((address_space(3))) void*)l, 16, 0, 0);
}

// pack 4 floats -> 4 OCP e4m3 bytes
__device__ __forceinline__ uint32_t pk4_fp8(float a, float b, float c, float d) {
  uint32_t v = 0;
  v = (uint32_t)__builtin_amdgcn_cvt_pk_fp8_f32(a, b, (int)v, false);
  v = (uint32_t)__builtin_amdgcn_cvt_pk_fp8_f32(c, d, (int)v, true);
  return v;
}

// accumulate 8 fp8 (uint2) into float[8]
__device__ __forceinline__ void acc_fp8x8(float* a, uint2 v) {
  a[0] += __builtin_amdgcn_cvt_f32_fp8(v.x, 0);
  a[1] += __builtin_amdgcn_cvt_f32_fp8(v.x, 1);
  a[2] += __builtin_amdgcn_cvt_f32_fp8(v.x, 2);
  a[3] += __builtin_amdgcn_cvt_f32_fp8(v.x, 3);
  a[4] += __builtin_amdgcn_cvt_f32_fp8(v.y, 0);
  a[5] += __builtin_amdgcn_cvt_f32_fp8(v.y, 1);
  a[6] += __builtin_amdgcn_cvt_f32_fp8(v.y, 2);
  a[7] += __builtin_amdgcn_cvt_f32_fp8(v.y, 3);
}

// ---------------- fused: x->bf16+fp8 convert | dst histogram + rank ----------------
// Hist blocks are INTERLEAVED (1-in-5) with convert blocks so the atomic-bound
// hist traffic overlaps the stream-bound convert instead of trailing it.
// The histogram atomic's return value IS the edge's within-row rank.
__global__ void k_cvtx_hist(const float* __restrict__ x, bf16* __restrict__ xb,
                            uint32_t* __restrict__ xq,
                            const int* __restrict__ dst, int* __restrict__ cnt,
                            uint16_t* __restrict__ rank) {
  int b = blockIdx.x;  // 31250 = 5 * 6250 blocks
  int m = b % 5;
  if (m < 4) {
    int cb = (b / 5) * 4 + m;  // 0..24999
    int t = cb * 256 + threadIdx.x;  // 4 elems / thread
    const float4 v = ((const float4*)x)[t];
    bf16x4 o;
    o.x = (bf16)v.x; o.y = (bf16)v.y; o.z = (bf16)v.z; o.w = (bf16)v.w;
    ((bf16x4*)xb)[t] = o;
    xq[t] = pk4_fp8(v.x, v.y, v.z, v.w);
  } else {
    int hb = b / 5;  // 0..6249
    int e = hb * 256 + threadIdx.x;
    int old = atomicAdd(&cnt[dst[e]], 1);
    rank[e] = (uint16_t)old;
  }
}

// ---------------- fused: weight packs | scan partials ----------------
// B1 = [W1l | W1r] as [256][512]; B2 = [W2l ; W2r] stacked as [256][256];
// Bd = [Wd1[:, :128] ; Wd1[:, 128:]] as [256][128]; biasPQ = [bd1 | 0] (256 f32).
__global__ void k_cvtw_scanpart(
    const float* __restrict__ W1l, const float* __restrict__ W1r,
    const float* __restrict__ W2l, const float* __restrict__ W2r,
    const float* __restrict__ Wd1, const float* __restrict__ bd1,
    bf16* __restrict__ B1, bf16* __restrict__ B2,
    bf16* __restrict__ Bd, float* __restrict__ biasPQ,
    const int* __restrict__ cnt, int* __restrict__ part, int N) {
  int b = blockIdx.x;
  if (b < NB_CVTW) {
    int g = b * 256 + threadIdx.x;  // 229632 total
    if (g < 131072) {
      int o = g >> 9, k = g & 511;
      float v = (k < 256) ? W1l[o * 256 + k] : W1r[o * 256 + k - 256];
      B1[g] = (bf16)v;
    } else if (g < 131072 + 65536) {
      int t = g - 131072;
      int o = t >> 8, k = t & 255;
      float v = (o < 128) ? W2l[o * 256 + k] : W2r[(o - 128) * 256 + k];
      B2[t] = (bf16)v;
    } else if (g < 131072 + 65536 + 32768) {
      int t = g - 196608;
      int o = t >> 7, k = t & 127;
      float v = (o < 128) ? Wd1[o * 256 + k] : Wd1[(o - 128) * 256 + 128 + k];
      Bd[t] = (bf16)v;
    } else if (g < 131072 + 65536 + 32768 + 256) {
      int t = g - 229376;
      biasPQ[t] = (t < 128) ? bd1[t] : 0.0f;
    }
  } else {
    __shared__ int sh[256];
    int bb = b - NB_CVTW;
    int t = threadIdx.x;
    int i = bb * 256 + t;
    sh[t] = (i < N) ? cnt[i] : 0;
    __syncthreads();
    for (int off = 128; off > 0; off >>= 1) {
      if (t < off) sh[t] += sh[t + off];
      __syncthreads();
    }
    if (t == 0) part[bb] = sh[0];
  }
}

__global__ __launch_bounds__(512) void k_scan_mid(int* __restrict__ part, int NB) {
  __shared__ int sh[512];
  int t = threadIdx.x;
  int v = (t < NB) ? part[t] : 0;
  sh[t] = v;
  __syncthreads();
  for (int off = 1; off < 512; off <<= 1) {
    int u = (t >= off) ? sh[t - off] : 0;
    __syncthreads();
    sh[t] += u;
    __syncthreads();
  }
  if (t < NB) part[t] = sh[t] - v;  // exclusive
}

__global__ void k_scan_fin(const int* __restrict__ cnt, const int* __restrict__ part,
                           int* __restrict__ rowptr, int N, int E) {
  __shared__ int sh[256];
  int t = threadIdx.x;
  int i = blockIdx.x * 256 + t;
  int v = (i < N) ? cnt[i] : 0;
  sh[t] = v;
  __syncthreads();
  for (int off = 1; off < 256; off <<= 1) {
    int u = (t >= off) ? sh[t - off] : 0;
    __syncthreads();
    sh[t] += u;
    __syncthreads();
  }
  if (i < N) rowptr[i] = part[blockIdx.x] + sh[t] - v;  // exclusive prefix
  if (i == 0) rowptr[N] = E;
}

// atomic-free CSR fill: pos = rowptr[dst] + rank (rank captured in hist).
// single int {src} scattered store per edge (4B -> 100K touched lines).
__global__ void k_fill(const int* __restrict__ src, const int* __restrict__ dst,
                       const int* __restrict__ rowptr,
                       const uint16_t* __restrict__ rank,
                       int* __restrict__ csr, int E) {
  int e = blockIdx.x * 256 + threadIdx.x;
  if (e < E) {
    int d = dst[e];
    int pos = rowptr[d] + (int)rank[e];
    csr[pos] = src[e];
  }
}

// ---------------- layer-1 mean aggregation (fp8 gather, 256 cols) ----------------
// one wave per node; half-wave per source row (32 lanes x 8B), 4-deep pipeline.
__global__ void k_agg(const uint8_t* __restrict__ xq, const int* __restrict__ rowptr,
                      const int* __restrict__ csr, bf16* __restrict__ mean) {
  int wave = threadIdx.x >> 6, lane = threadIdx.x & 63;
  int n = blockIdx.x * 4 + wave;
  int s = rowptr[n], e = rowptr[n + 1];
  int half = lane >> 5, l32 = lane & 31;
  float a[8] = {};
  const uint8_t* base = xq + l32 * 8;
  int i = s + half;
  for (; i + 6 < e; i += 8) {
    int c0 = csr[i], c1 = csr[i + 2], c2 = csr[i + 4], c3 = csr[i + 6];
    uint2 v0 = *(const uint2*)(base + (size_t)c0 * 256);
    uint2 v1 = *(const uint2*)(base + (size_t)c1 * 256);
    uint2 v2 = *(const uint2*)(base + (size_t)c2 * 256);
    uint2 v3 = *(const uint2*)(base + (size_t)c3 * 256);
    acc_fp8x8(a, v0); acc_fp8x8(a, v1); acc_fp8x8(a, v2); acc_fp8x8(a, v3);
  }
  for (; i < e; i += 2) {
    uint2 v = *(const uint2*)(base + (size_t)csr[i] * 256);
    acc_fp8x8(a, v);
  }
  int deg = e - s;
  float sc = 1.0f / (float)(deg > 0 ? deg : 1);
  bf16x8 o;
#pragma unroll
  for (int j = 0; j < 8; ++j) {
    float t = a[j] + __shfl_xor(a[j], 32);
    o[j] = (bf16)(t * sc);
  }
  if (half == 0)
    *(bf16x8*)(mean + (size_t)n * 256 + l32 * 8) = o;
}

// ---------------- layer-2 aggregate+combine (fp8 hl gather, 128 cols) ----------------
// zf[n] = agg_mean(hq over neighbors) + hr[n] + b2l. Quarter-wave per row,
// 2-deep pipeline.
__global__ void k_agg2z(const uint8_t* __restrict__ hq, const bf16* __restrict__ hr,
                        const int* __restrict__ rowptr, const int* __restrict__ csr,
                        const float* __restrict__ b2l, bf16* __restrict__ zf) {
  int wave = threadIdx.x >> 6, lane = threadIdx.x & 63;
  int n = blockIdx.x * 4 + wave;
  int s = rowptr[n], e = rowptr[n + 1];
  int sub = lane >> 4, l16 = lane & 15;
  float a[8] = {};
  const uint8_t* base = hq + l16 * 8;
  int i = s + sub;
  for (; i + 4 < e; i += 8) {
    int c0 = csr[i], c1 = csr[i + 4];
    uint2 v0 = *(const uint2*)(base + (size_t)c0 * 128);
    uint2 v1 = *(const uint2*)(base + (size_t)c1 * 128);
    acc_fp8x8(a, v0); acc_fp8x8(a, v1);
  }
  for (; i < e; i += 4) {
    uint2 v = *(const uint2*)(base + (size_t)csr[i] * 128);
    acc_fp8x8(a, v);
  }
  int deg = e - s;
  float sc = 1.0f / (float)(deg > 0 ? deg : 1);
  bf16x8 hv = *(const bf16x8*)(hr + (size_t)n * 128 + l16 * 8);
  const float4* b4 = (const float4*)(b2l + l16 * 8);
  float4 ba = b4[0], bb = b4[1];
  float bl[8] = {ba.x, ba.y, ba.z, ba.w, bb.x, bb.y, bb.z, bb.w};
  bf16x8 o;
#pragma unroll
  for (int j = 0; j < 8; ++j) {
    float t = a[j];
    t += __shfl_xor(t, 16);
    t += __shfl_xor(t, 32);
    o[j] = (bf16)(t * sc + (float)hv[j] + bl[j]);
  }
  if (sub == 0)
    *(bf16x8*)(zf + (size_t)n * 128 + l16 * 8) = o;
}

// ---------------- SAGEConv1 GEMM: h = relu([mean|x] @ B1^T + b1l) ----------------
// grid (2, 782): col-tile fastest for twin-block A reuse.
__global__ __launch_bounds__(256) void k_conv_gemm(
    const bf16* __restrict__ A1, const bf16* __restrict__ A2,
    const bf16* __restrict__ B, const float* __restrict__ bias,
    bf16* __restrict__ out, int Nrows) {
  __shared__ bf16 As[128 * 64];
  __shared__ bf16 Bs[128 * 64];
  const int tid = threadIdx.x, wave = tid >> 6, lane = tid & 63;
  const int quad = lane >> 4, l16 = lane & 15;
  const int rowBase = blockIdx.y * 128;
  const int colBase = blockIdx.x * 128;
  const int wr = (wave >> 1) * 64;
  const int wc = (wave & 1) * 64;
  floatx4 acc[4][4] = {};

  for (int kc = 0; kc < 8; ++kc) {
    const bf16* Asrc = (kc < 4) ? A1 : A2;
    const int kb = (kc & 3) * 64;
    for (int i = 0; i < 4; ++i) {
      int u = wave * 256 + i * 64 + lane;
      int row = u >> 3, seg = u & 7;
      int sg = seg ^ (row & 7);  // swizzled global seg -> LDS seg
      int node = rowBase + row;
      if (node >= Nrows) node = Nrows - 1;
      async16(Asrc + (size_t)node * 256 + kb + sg * 8, &As[(wave * 256 + i * 64) * 8]);
    }
    for (int i = 0; i < 4; ++i) {
      int u = wave * 256 + i * 64 + lane;
      int row = u >> 3, seg = u & 7;
      int sg = seg ^ (row & 7);
      async16(B + (size_t)(colBase + row) * 512 + kc * 64 + sg * 8,
              &Bs[(wave * 256 + i * 64) * 8]);
    }
    __syncthreads();
    for (int ks = 0; ks < 2; ++ks) {
      bf16x8 af[4], bq[4];
      const int sw = (ks * 4 + quad) ^ (l16 & 7);
      for (int mt = 0; mt < 4; ++mt)
        af[mt] = *(const bf16x8*)&As[(wr + mt * 16 + l16) * 64 + sw * 8];
      for (int nt = 0; nt < 4; ++nt)
        bq[nt] = *(const bf16x8*)&Bs[(wc + nt * 16 + l16) * 64 + sw * 8];
      for (int mt = 0; mt < 4; ++mt)
        for (int nt = 0; nt < 4; ++nt)
          acc[mt][nt] = __builtin_amdgcn_mfma_f32_16x16x32_bf16(af[mt], bq[nt], acc[mt][nt], 0, 0, 0);
    }
    __syncthreads();
  }
  float bv[4];
  for (int nt = 0; nt < 4; ++nt) bv[nt] = bias[colBase + wc + nt * 16 + l16];
  for (int mt = 0; mt < 4; ++mt)
    for (int nt = 0; nt < 4; ++nt) {
      int gcol = colBase + wc + nt * 16 + l16;
      for (int r = 0; r < 4; ++r) {
        int grow = rowBase + wr + mt * 16 + quad * 4 + r;
        if (grow < Nrows) {
          float v = fmaxf(acc[mt][nt][r] + bv[nt], 0.0f);
          out[(size_t)grow * 256 + gcol] = (bf16)v;
        }
      }
    }
}

// ---------------- generic GEMM with split epilogue ----------------
// out = A[N][KDIM] @ B[256][KDIM]^T (+bias). 256 output cols split:
// EPI=1: cols<128 -> fp8 out1 [N][128], cols>=128 -> bf16 out2 [N][128] (no bias)
// EPI=2: cols<128 -> bf16 out1 (+bias), cols>=128 -> bf16 out2 (+bias)
template <int KDIM, int EPI>
__global__ __launch_bounds__(256) void k_gemm(
    const bf16* __restrict__ A, const bf16* __restrict__ B,
    const float* __restrict__ bias, void* __restrict__ out1,
    void* __restrict__ out2, int Nrows) {
  __shared__ bf16 As[128 * 64];
  __shared__ bf16 Bs[128 * 64];
  const int tid = threadIdx.x, wave = tid >> 6, lane = tid & 63;
  const int quad = lane >> 4, l16 = lane & 15;
  const int rowBase = blockIdx.y * 128;
  const int colBase = blockIdx.x * 128;
  const int wr = (wave >> 1) * 64;
  const int wc = (wave & 1) * 64;
  floatx4 acc[4][4] = {};

  for (int kc = 0; kc < KDIM / 64; ++kc) {
    for (int i = 0; i < 4; ++i) {
      int u = wave * 256 + i * 64 + lane;
      int row = u >> 3, seg = u & 7;
      int sg = seg ^ (row & 7);
      int node = rowBase + row;
      if (node >= Nrows) node = Nrows - 1;
      async16(A + (size_t)node * KDIM + kc * 64 + sg * 8, &As[(wave * 256 + i * 64) * 8]);
    }
    for (int i = 0; i < 4; ++i) {
      int u = wave * 256 + i * 64 + lane;
      int row = u >> 3, seg = u & 7;
      int sg = seg ^ (row & 7);
      async16(B + (size_t)(colBase + row) * KDIM + kc * 64 + sg * 8,
              &Bs[(wave * 256 + i * 64) * 8]);
    }
    __syncthreads();
    for (int ks = 0; ks < 2; ++ks) {
      bf16x8 af[4], bq[4];
      const int sw = (ks * 4 + quad) ^ (l16 & 7);
      for (int mt = 0; mt < 4; ++mt)
        af[mt] = *(const bf16x8*)&As[(wr + mt * 16 + l16) * 64 + sw * 8];
      for (int nt = 0; nt < 4; ++nt)
        bq[nt] = *(const bf16x8*)&Bs[(wc + nt * 16 + l16) * 64 + sw * 8];
      for (int mt = 0; mt < 4; ++mt)
        for (int nt = 0; nt < 4; ++nt)
          acc[mt][nt] = __builtin_amdgcn_mfma_f32_16x16x32_bf16(af[mt], bq[nt], acc[mt][nt], 0, 0, 0);
    }
    __syncthreads();
  }
  float bv[4];
  for (int nt = 0; nt < 4; ++nt)
    bv[nt] = (EPI == 2) ? bias[colBase + wc + nt * 16 + l16] : 0.0f;
  const bool lowHalf = (colBase == 0);  // 256-col output, tile 0 = cols<128
  for (int mt = 0; mt < 4; ++mt)
    for (int nt = 0; nt < 4; ++nt) {
      int gcol = colBase + wc + nt * 16 + l16;
      for (int r = 0; r < 4; ++r) {
        int grow = rowBase + wr + mt * 16 + quad * 4 + r;
        if (grow < Nrows) {
          float v = acc[mt][nt][r] + bv[nt];
          if (lowHalf) {
            if (EPI == 1) {
              uint32_t pk = (uint32_t)__builtin_amdgcn_cvt_pk_fp8_f32(v, v, 0, false);
              ((uint8_t*)out1)[(size_t)grow * 128 + gcol] = (uint8_t)pk;
            } else {
              ((bf16*)out1)[(size_t)grow * 128 + gcol] = (bf16)v;
            }
          } else {
            ((bf16*)out2)[(size_t)grow * 128 + gcol - 128] = (bf16)v;
          }
        }
      }
    }
}

// ---------------- edge decoder, CSR-ordered ----------------
// outCSR[pos] = sum_o relu(P[src][o]+Q[d][o]) * wd2[o] + bd2 -- written
// SEQUENTIALLY at the CSR position; a permute pass reorders to edge order.
// one wave per dst node; quarter-wave (16 lanes x 8 cols) per edge.
__global__ __launch_bounds__(256) void k_edge(
    const bf16* __restrict__ P, const bf16* __restrict__ Q,
    const int* __restrict__ rowptr, const int* __restrict__ csr,
    const float* __restrict__ wd2, const float* __restrict__ bd2,
    float* __restrict__ outCSR) {
  int wave = threadIdx.x >> 6, lane = threadIdx.x & 63;
  int n = blockIdx.x * 4 + wave;
  int s = rowptr[n], e = rowptr[n + 1];
  int sub = lane >> 4, l16 = lane & 15;
  bf16x8 qv = *(const bf16x8*)(Q + (size_t)n * 128 + l16 * 8);
  float qf[8];
#pragma unroll
  for (int j = 0; j < 8; ++j) qf[j] = (float)qv[j];
  const float4* w4 = (const float4*)(wd2 + l16 * 8);
  float4 wa = w4[0], wb = w4[1];
  float w[8] = {wa.x, wa.y, wa.z, wa.w, wb.x, wb.y, wb.z, wb.w};
  const float bout = bd2[0];
  int i = s + sub;
  for (; i + 4 < e; i += 8) {
    int c0 = csr[i], c1 = csr[i + 4];
    bf16x8 p0 = *(const bf16x8*)(P + (size_t)c0 * 128 + l16 * 8);
    bf16x8 p1 = *(const bf16x8*)(P + (size_t)c1 * 128 + l16 * 8);
    float a0 = 0.f, a1 = 0.f;
#pragma unroll
    for (int j = 0; j < 8; ++j) {
      a0 += fmaxf((float)p0[j] + qf[j], 0.f) * w[j];
      a1 += fmaxf((float)p1[j] + qf[j], 0.f) * w[j];
    }
    a0 += __shfl_xor(a0, 1); a1 += __shfl_xor(a1, 1);
    a0 += __shfl_xor(a0, 2); a1 += __shfl_xor(a1, 2);
    a0 += __shfl_xor(a0, 4); a1 += __shfl_xor(a1, 4);
    a0 += __shfl_xor(a0, 8); a1 += __shfl_xor(a1, 8);
    if (l16 == 0) { outCSR[i] = a0 + bout; outCSR[i + 4] = a1 + bout; }
  }
  for (; i < e; i += 4) {
    int c = csr[i];
    bf16x8 p = *(const bf16x8*)(P + (size_t)c * 128 + l16 * 8);
    float a = 0.f;
#pragma unroll
    for (int j = 0; j < 8; ++j)
      a += fmaxf((float)p[j] + qf[j], 0.f) * w[j];
    a += __shfl_xor(a, 1);
    a += __shfl_xor(a, 2);
    a += __shfl_xor(a, 4);
    a += __shfl_xor(a, 8);
    if (l16 == 0) outCSR[i] = a + bout;
  }
}

// ---------------- permute CSR-order results to edge order ----------------
// out[e] = outCSR[rowptr[dst[e]] + rank[e]]; gathers are L2/LLC-resident.
__global__ void k_perm(const int* __restrict__ dst, const uint16_t* __restrict__ rank,
                       const int* __restrict__ rowptr, const float* __restrict__ outCSR,
                       float* __restrict__ out, int E) {
  int e = blockIdx.x * 256 + threadIdx.x;
  if (e < E) {
    int d = dst[e];
    out[e] = outCSR[rowptr[d] + (int)rank[e]];
  }
}

// ---------------- host ----------------
extern "C" void kernel_launch(void* const* d_in, const int* in_sizes, int n_in,
                              void* d_out, int out_size, void* d_ws, size_t ws_size,
                              hipStream_t stream) {
  const float* x   = (const float*)d_in[0];
  const int*   ei  = (const int*)d_in[1];
  const float* W1l = (const float*)d_in[2];
  const float* b1l = (const float*)d_in[3];
  const float* W1r = (const float*)d_in[4];
  const float* W2l = (const float*)d_in[5];
  const float* b2l = (const float*)d_in[6];
  const float* W2r = (const float*)d_in[7];
  const float* Wd1 = (const float*)d_in[8];
  const float* bd1 = (const float*)d_in[9];
  const float* Wd2 = (const float*)d_in[10];
  const float* bd2 = (const float*)d_in[11];
  float* out = (float*)d_out;

  const int N = NN, E = NE;
  const int* srcv = ei;
  const int* dstv = ei + E;

  char* w = (char*)d_ws;
  size_t off = 0;
  auto take = [&](size_t bytes) {
    size_t o = off;
    off = (off + bytes + 255) & ~(size_t)255;
    return o;
  };
  int*      cnt    = (int*)(w + take((size_t)N * 4));
  int*      rowptr = (int*)(w + take((size_t)(N + 1) * 4));
  int*      part   = (int*)(w + take((size_t)NB_SCAN * 4));
  uint16_t* rank   = (uint16_t*)(w + take((size_t)E * 2));
  int*      csr    = (int*)(w + take((size_t)E * 4));
  float*    outCSR = (float*)(w + take((size_t)E * 4));
  bf16*     xb     = (bf16*)(w + take((size_t)N * 256 * 2));
  uint8_t*  xq     = (uint8_t*)(w + take((size_t)N * 256));
  bf16*     mean   = (bf16*)(w + take((size_t)N * 256 * 2));  // reused: hq+hr
  bf16*     h      = (bf16*)(w + take((size_t)N * 256 * 2));  // reused: P+Q
  bf16*     zf     = (bf16*)(w + take((size_t)N * 128 * 2));
  bf16*     B1     = (bf16*)(w + take((size_t)131072 * 2));
  bf16*     B2     = (bf16*)(w + take((size_t)65536 * 2));
  bf16*     Bd     = (bf16*)(w + take((size_t)32768 * 2));
  float*    biasPQ = (float*)(w + take((size_t)256 * 4));
  // aliases (producer/consumer ordering makes these safe):
  uint8_t* hq = (uint8_t*)mean;                 // [N][128] fp8, after conv1
  bf16*    hr = (bf16*)(hq + (size_t)N * 128);  // [N][128] bf16
  bf16*    P  = h;                              // [N][128] bf16, after gemm256
  bf16*    Q  = h + (size_t)N * 128;            // [N][128] bf16
  (void)ws_size; (void)n_in; (void)in_sizes; (void)out_size;

  hipMemsetAsync(cnt, 0, (size_t)N * 4, stream);

  k_cvtx_hist<<<NB_CVTX + NB_HIST, 256, 0, stream>>>(x, xb, (uint32_t*)xq, dstv, cnt, rank);
  k_cvtw_scanpart<<<NB_CVTW + NB_SCAN, 256, 0, stream>>>(
      W1l, W1r, W2l, W2r, Wd1, bd1, B1, B2, Bd, biasPQ, cnt, part, N);
  k_scan_mid<<<1, 512, 0, stream>>>(part, NB_SCAN);
  k_scan_fin<<<NB_SCAN, 256, 0, stream>>>(cnt, part, rowptr, N, E);
  k_fill<<<E / 256, 256, 0, stream>>>(srcv, dstv, rowptr, rank, csr, E);

  // conv1: h = relu([mean|x] @ [W1l|W1r]^T + b1l)
  k_agg<<<N / 4, 256, 0, stream>>>(xq, rowptr, csr, mean);
  k_conv_gemm<<<dim3(2, 782), 256, 0, stream>>>(mean, xb, B1, b1l, h, N);
  // conv2 (transform-then-aggregate): [hq|hr] = h @ [W2l;W2r]^T (hq fp8),
  // then zf = agg_mean(hq) + hr + b2l
  k_gemm<256, 1><<<dim3(2, 782), 256, 0, stream>>>(h, B2, nullptr, hq, hr, N);
  k_agg2z<<<N / 4, 256, 0, stream>>>(hq, hr, rowptr, csr, b2l, zf);
  // decoder node-level: [P|Q] = zf @ Bd^T + [bd1|0]
  k_gemm<128, 2><<<dim3(2, 782), 256, 0, stream>>>(zf, Bd, biasPQ, P, Q, N);
  // decoder edge-level, CSR-ordered (Q dense per node, P gathered, seq write)
  k_edge<<<N / 4, 256, 0, stream>>>(P, Q, rowptr, csr, Wd2, bd2, outCSR);
  // reorder to edge order
  k_perm<<<E / 256, 256, 0, stream>>>(dstv, rank, rowptr, outCSR, out, E);
}